// Round 1
// baseline (595.305 us; speedup 1.0000x reference)
//
#include <hip/hip_runtime.h>

constexpr int N_NODES = 100000;
constexpr int F_IN    = 32;
constexpr int H       = 128;
constexpr int OUT_F   = 200;
constexpr int NEDGES  = 1600000;
constexpr float EPS   = 1e-5f;
constexpr int NXCD    = 8;

constexpr int HIST8_BLKS = (NEDGES / 8 + 255) / 256;  // 782
constexpr int WS_BLKS    = 80;                        // 5*128*128/1024
constexpr int NPARTS     = (N_NODES + 255) / 256;     // 391
constexpr int FILL_BLKS  = (NEDGES / 4 + 255) / 256;  // 1563
constexpr int TILE_BLKS  = (N_NODES + 63) / 64;       // 1563
constexpr int PRE3_BLKS  = HIST8_BLKS + TILE_BLKS;    // 2345 (1:2 interleave)
constexpr int MM_BLKS    = TILE_BLKS * 2;             // 3126 (64r x 64c tiles)

typedef __attribute__((ext_vector_type(8))) short  short8;
typedef __attribute__((ext_vector_type(4))) float  f32x4;
typedef __attribute__((ext_vector_type(2))) float  fv2;

__device__ __forceinline__ void fma4(float4& a, float s, const float4& w) {
  a.x = fmaf(s, w.x, a.x); a.y = fmaf(s, w.y, a.y);
  a.z = fmaf(s, w.z, a.z); a.w = fmaf(s, w.w, a.w);
}

__device__ __forceinline__ unsigned short f2bf(float f) {  // RNE
  union { float f; unsigned u; } v; v.f = f;
  unsigned r = v.u + 0x7fffu + ((v.u >> 16) & 1u);
  return (unsigned short)(r >> 16);
}
__device__ __forceinline__ float bf2f(unsigned short s) {
  union { unsigned u; float f; } v; v.u = ((unsigned)s) << 16;
  return v.f;
}
__device__ __forceinline__ float bflo(unsigned u) { return __uint_as_float(u << 16); }
__device__ __forceinline__ float bfhi(unsigned u) { return __uint_as_float(u & 0xffff0000u); }
__device__ __forceinline__ unsigned pack2(float lo, float hi) {
  return (unsigned)f2bf(lo) | ((unsigned)f2bf(hi) << 16);
}
__device__ __forceinline__ void st_bf4(unsigned short* p, float4 v) {
  uint2 o; o.x = pack2(v.x, v.y); o.y = pack2(v.z, v.w);
  *(uint2*)p = o;
}

// ---------------- fp8 e4m3fn helpers ----------------
#if __has_builtin(__builtin_amdgcn_cvt_pk_f32_fp8) && __has_builtin(__builtin_amdgcn_cvt_pk_fp8_f32)
#define HAVE_FP8_CVT 1
#endif

#ifndef HAVE_FP8_CVT
__device__ __forceinline__ float fp8_dec1(unsigned b) {
  unsigned s = (b >> 7) & 1u, E = (b >> 3) & 15u, m = b & 7u;
  float v;
  if (E) {
    union { unsigned u; float f; } t;
    t.u = (s << 31) | ((E + 120u) << 23) | (m << 20);
    v = t.f;
  } else {
    v = (s ? -1.f : 1.f) * (float)m * 0.001953125f;
  }
  return v;
}
#endif

template <bool HI>
__device__ __forceinline__ fv2 fp8x2(unsigned u) {
#ifdef HAVE_FP8_CVT
  return __builtin_amdgcn_cvt_pk_f32_fp8((int)u, HI);
#else
  unsigned p = HI ? (u >> 16) : u;
  fv2 r; r.x = fp8_dec1(p & 0xffu); r.y = fp8_dec1((p >> 8) & 0xffu);
  return r;
#endif
}

__device__ __forceinline__ unsigned char f32_to_fp8(float f) {
#ifdef HAVE_FP8_CVT
  return (unsigned char)(__builtin_amdgcn_cvt_pk_fp8_f32(f, f, 0, false) & 0xff);
#else
  union { float f; unsigned u; } t; t.f = f;
  unsigned s = t.u >> 31;
  float a = fabsf(f);
  if (a > 448.f) a = 448.f;
  t.f = a;
  int e = (int)((t.u >> 23) & 0xff) - 127;
  unsigned char r;
  if (a == 0.f) {
    r = 0;
  } else if (e >= -6) {
    unsigned m = t.u & 0x7fffffu;
    unsigned keep = m >> 20, rest = m & 0xfffffu;
    keep += (rest > 0x80000u) || (rest == 0x80000u && (keep & 1u));
    int E = e + 7;
    if (keep == 8u) { keep = 0u; E += 1; }
    if (E >= 16) { E = 15; keep = 6u; }
    r = (unsigned char)((E << 3) | keep);
  } else {
    int mi = (int)(a * 512.f + 0.5f);
    r = (mi > 7) ? (unsigned char)(1u << 3) : (unsigned char)mi;
  }
  return (unsigned char)(r | (s << 7));
#endif
}

// ---------------- k_ws: W -> bf16 transposed ----------------
__global__ void k_ws(const float* __restrict__ W_conv,
                     const float* __restrict__ W_res,
                     unsigned short* __restrict__ whiT) {
  int base = blockIdx.x * 1024;
#pragma unroll
  for (int j = 0; j < 4; ++j) {
    int idx = base + j * 256 + threadIdx.x;
    if (idx < 5 * H * H) {
      int m = idx >> 14, rr = idx & 16383;
      int k = rr >> 7, n = rr & 127;
      const float* src = (m < 4) ? (W_conv + m * H * H) : W_res;
      whiT[m * H * H + n * H + k] = f2bf(src[k * H + n]);
    }
  }
}

// mm from LDS tile: 64 rows x 128 cols, wave = 32r x 64c (B frags hoisted)
__device__ __forceinline__ void mm_lds_fp8(const unsigned short* sA,
                                           const unsigned short* __restrict__ WT,
                                           int n0, int t,
                                           unsigned char* __restrict__ htOut) {
  int wave = t >> 6, lane = t & 63;
  int wr = wave >> 1, wc = wave & 1;
  int m = lane & 15, quad = (lane >> 4) & 3;
  short8 bh[4][4];
#pragma unroll
  for (int q = 0; q < 4; ++q)
#pragma unroll
    for (int ct = 0; ct < 4; ++ct) {
      int n = wc * 64 + ct * 16 + m;
      bh[q][ct] = *(const short8*)(WT + n * H + q * 32 + quad * 8);
    }
  f32x4 acc[2][4];
#pragma unroll
  for (int i = 0; i < 2; ++i)
#pragma unroll
    for (int j = 0; j < 4; ++j) acc[i][j] = (f32x4){0.f, 0.f, 0.f, 0.f};
#pragma unroll
  for (int q = 0; q < 4; ++q) {
    short8 ah[2];
#pragma unroll
    for (int rt = 0; rt < 2; ++rt)
      ah[rt] = *(const short8*)(sA + (wr * 32 + rt * 16 + m) * 136 + q * 32 + quad * 8);
#pragma unroll
    for (int rt = 0; rt < 2; ++rt)
#pragma unroll
      for (int ct = 0; ct < 4; ++ct)
        acc[rt][ct] = __builtin_amdgcn_mfma_f32_16x16x32_bf16(ah[rt], bh[q][ct], acc[rt][ct], 0, 0, 0);
  }
#pragma unroll
  for (int rt = 0; rt < 2; ++rt)
#pragma unroll
    for (int ct = 0; ct < 4; ++ct) {
      int col = wc * 64 + ct * 16 + m;
#pragma unroll
      for (int rr = 0; rr < 4; ++rr) {
        int gn = n0 + wr * 32 + rt * 16 + quad * 4 + rr;
        if (gn < N_NODES) htOut[(size_t)gn * H + col] = f32_to_fp8(acc[rt][ct][rr]);
      }
    }
}

// ---------------- k_pre3: hist | (embed 64-node tile -> LDS -> mm W0), 1:2 ----------------
// r16: histogram privatized per physical XCD (HW_REG_XCC_ID) with
// WORKGROUP-scope atomic RMW: drops sc1, so the add executes in the local
// XCD's L2 (shared by all CUs of that XCD -> per-slice atomicity holds;
// each slice is touched by exactly one XCD). Device-scope (sc1) atomics
// serialize at the shared memory-side point (~8/cycle measured: 1.6M ops
// == 192K cycles == whole kernel). Cross-XCD combine happens in k_scan_a
// after the dispatch-end release. ranks = (xcd<<8)|rank (per-XCD rank < 256).
__global__ __launch_bounds__(256) void k_pre3(
    const int* __restrict__ ei, int* __restrict__ deg8,
    unsigned short* __restrict__ ranks16,
    const float* __restrict__ x, const float* __restrict__ W_emb,
    const float* __restrict__ b_emb, unsigned short* __restrict__ h,
    const unsigned short* __restrict__ W0T, unsigned char* __restrict__ ht8) {
  __shared__ __align__(16) char smem[25600];
  int t = threadIdx.x;
  int id = blockIdx.x;
  int q3 = id / 3, r3 = id - q3 * 3;
  if (r3 == 0) {
    unsigned xcd;
    asm("s_getreg_b32 %0, hwreg(HW_REG_XCC_ID)" : "=s"(xcd));
    xcd &= 7u;
    int* dslice = deg8 + (size_t)xcd * N_NODES;
    unsigned hx = xcd << 8;
    int i = q3 * 256 + t;
    if (i < NEDGES / 8) {
      int4 a = *(const int4*)(ei + NEDGES + 8 * i);
      int4 b = *(const int4*)(ei + NEDGES + 8 * i + 4);
      union { unsigned short u16[8]; uint4 u4; } rr;
      rr.u16[0] = (unsigned short)(hx | (unsigned)__hip_atomic_fetch_add(dslice + a.x, 1, __ATOMIC_RELAXED, __HIP_MEMORY_SCOPE_WORKGROUP));
      rr.u16[1] = (unsigned short)(hx | (unsigned)__hip_atomic_fetch_add(dslice + a.y, 1, __ATOMIC_RELAXED, __HIP_MEMORY_SCOPE_WORKGROUP));
      rr.u16[2] = (unsigned short)(hx | (unsigned)__hip_atomic_fetch_add(dslice + a.z, 1, __ATOMIC_RELAXED, __HIP_MEMORY_SCOPE_WORKGROUP));
      rr.u16[3] = (unsigned short)(hx | (unsigned)__hip_atomic_fetch_add(dslice + a.w, 1, __ATOMIC_RELAXED, __HIP_MEMORY_SCOPE_WORKGROUP));
      rr.u16[4] = (unsigned short)(hx | (unsigned)__hip_atomic_fetch_add(dslice + b.x, 1, __ATOMIC_RELAXED, __HIP_MEMORY_SCOPE_WORKGROUP));
      rr.u16[5] = (unsigned short)(hx | (unsigned)__hip_atomic_fetch_add(dslice + b.y, 1, __ATOMIC_RELAXED, __HIP_MEMORY_SCOPE_WORKGROUP));
      rr.u16[6] = (unsigned short)(hx | (unsigned)__hip_atomic_fetch_add(dslice + b.z, 1, __ATOMIC_RELAXED, __HIP_MEMORY_SCOPE_WORKGROUP));
      rr.u16[7] = (unsigned short)(hx | (unsigned)__hip_atomic_fetch_add(dslice + b.w, 1, __ATOMIC_RELAXED, __HIP_MEMORY_SCOPE_WORKGROUP));
      ((uint4*)ranks16)[i] = rr.u4;
    }
  } else {
    int j = q3 * 2 + (r3 - 1);
    int n0 = j * 64;
    float* sW = (float*)smem;
    float* sX = sW + 4096;
    unsigned short* sH = (unsigned short*)smem;
#pragma unroll
    for (int p = 0; p < 4; ++p)
      ((float4*)sW)[t + p * 256] = ((const float4*)W_emb)[t + p * 256];
#pragma unroll
    for (int p = 0; p < 2; ++p) {
      int fi = t * 2 + p;
      int row = fi >> 3, k4 = (fi & 7) * 4;
      int gn = n0 + row; if (gn >= N_NODES) gn = N_NODES - 1;
      *(float4*)(sX + row * 36 + k4) = *(const float4*)(x + (size_t)gn * F_IN + k4);
    }
    __syncthreads();
    // conflict-free sW reads: col0 = (t&3)*4 -> banks {0,4,8,12}(+16i)
    int nr = t >> 2, col0 = (t & 3) * 4;
    float4 acc[8];
#pragma unroll
    for (int i = 0; i < 8; ++i) acc[i] = make_float4(0.f, 0.f, 0.f, 0.f);
#pragma unroll 4
    for (int k = 0; k < F_IN; ++k) {
      float xv = sX[nr * 36 + k];
      const float* wp = sW + k * H + col0;
#pragma unroll
      for (int i = 0; i < 8; ++i) fma4(acc[i], xv, *(const float4*)(wp + i * 16));
    }
#pragma unroll
    for (int i = 0; i < 8; ++i) {
      float4 bv = *(const float4*)(b_emb + col0 + i * 16);
      acc[i].x += bv.x; acc[i].y += bv.y; acc[i].z += bv.z; acc[i].w += bv.w;
    }
    __syncthreads();  // done reading sW/sX; reuse as sH
    int node = n0 + nr;
    unsigned short* hr = h + (size_t)node * H + col0;
#pragma unroll
    for (int i = 0; i < 8; ++i) {
      st_bf4(sH + nr * 136 + col0 + i * 16, acc[i]);
      if (node < N_NODES) st_bf4(hr + i * 16, acc[i]);
    }
    __syncthreads();
    mm_lds_fp8(sH, W0T, n0, t, ht8);
  }
}

// ---------------- scans ----------------
// r16: folds the 8 per-XCD histogram slices: per node, total degree +
// per-XCD exclusive prefix -> xoff[8][N] (slice 0 == plain node base).
__global__ void k_scan_a(const int* __restrict__ deg8, int* __restrict__ degT,
                         int* __restrict__ xoff, int* __restrict__ parts,
                         float* __restrict__ dinv) {
  __shared__ int s[256];
  int i = blockIdx.x * 256 + threadIdx.x;
  int d[NXCD];
  int tot = 0;
#pragma unroll
  for (int c = 0; c < NXCD; ++c) {
    d[c] = (i < N_NODES) ? deg8[(size_t)c * N_NODES + i] : 0;
    tot += d[c];
  }
  s[threadIdx.x] = tot;
  __syncthreads();
#pragma unroll
  for (int off = 1; off < 256; off <<= 1) {
    int v = (threadIdx.x >= off) ? s[threadIdx.x - off] : 0;
    __syncthreads();
    s[threadIdx.x] += v;
    __syncthreads();
  }
  if (i < N_NODES) {
    int base = s[threadIdx.x] - tot;   // block-local exclusive
    degT[i] = tot;
    dinv[i] = rsqrtf((float)(tot + 1));
    int p = base;
#pragma unroll
    for (int c = 0; c < NXCD; ++c) {
      xoff[(size_t)c * N_NODES + i] = p;
      p += d[c];
    }
  }
  if (threadIdx.x == 255) parts[blockIdx.x] = s[255];
}

__global__ void k_scan_b(int* __restrict__ parts, int nparts) {
  __shared__ int s[512];
  int t = threadIdx.x;
  int d = (t < nparts) ? parts[t] : 0;
  s[t] = d;
  __syncthreads();
#pragma unroll
  for (int off = 1; off < 512; off <<= 1) {
    int v = (t >= off) ? s[t - off] : 0;
    __syncthreads();
    s[t] += v;
    __syncthreads();
  }
  if (t < nparts) parts[t] = s[t] - d;
}

// ---------------- k_fill ----------------
__global__ __launch_bounds__(256) void k_fill(
    const int* __restrict__ ei, const unsigned short* __restrict__ ranks16,
    const int* __restrict__ xoff, const int* __restrict__ parts,
    const float* __restrict__ dinv, unsigned* __restrict__ csr) {
  int i = blockIdx.x * 256 + threadIdx.x;
  if (i < NEDGES / 4) {
    int4 s4 = *(const int4*)(ei + 4 * i);
    int4 d4 = *(const int4*)(ei + NEDGES + 4 * i);
    uint2 rv = ((const uint2*)ranks16)[i];
    unsigned r0 = rv.x & 0xffffu, r1 = rv.x >> 16;
    unsigned r2 = rv.y & 0xffffu, r3 = rv.y >> 16;
    int p0 = xoff[(size_t)(r0 >> 8) * N_NODES + d4.x] + parts[d4.x >> 8] + (int)(r0 & 255u);
    int p1 = xoff[(size_t)(r1 >> 8) * N_NODES + d4.y] + parts[d4.y >> 8] + (int)(r1 & 255u);
    int p2 = xoff[(size_t)(r2 >> 8) * N_NODES + d4.z] + parts[d4.z >> 8] + (int)(r2 & 255u);
    int p3 = xoff[(size_t)(r3 >> 8) * N_NODES + d4.w] + parts[d4.w >> 8] + (int)(r3 & 255u);
    csr[p0] = ((unsigned)s4.x << 15) | (unsigned)(dinv[s4.x] * 32767.f + 0.5f);
    csr[p1] = ((unsigned)s4.y << 15) | (unsigned)(dinv[s4.y] * 32767.f + 0.5f);
    csr[p2] = ((unsigned)s4.z << 15) | (unsigned)(dinv[s4.z] * 32767.f + 0.5f);
    csr[p3] = ((unsigned)s4.w << 15) | (unsigned)(dinv[s4.w] * 32767.f + 0.5f);
  }
}

// ---------------- mm core for layers 1-3 (global A) ----------------
struct MMAcc { f32x4 a[2][2]; };

__device__ __forceinline__ MMAcc mm_core(const unsigned short* __restrict__ A,
                                         const unsigned short* __restrict__ WhiT,
                                         int n0, int c0, int t,
                                         unsigned short* sA) {
  int wave = t >> 6, lane = t & 63;
  int wr = wave >> 1, wc = wave & 1;
  int m = lane & 15, quad = (lane >> 4) & 3;
  short8 bh[4][2];
#pragma unroll
  for (int q = 0; q < 4; ++q)
#pragma unroll
    for (int ct = 0; ct < 2; ++ct) {
      int n = c0 + wc * 32 + ct * 16 + m;
      bh[q][ct] = *(const short8*)(WhiT + n * H + q * 32 + quad * 8);
    }
#pragma unroll
  for (int p = 0; p < 4; ++p) {
    int fi = t + p * 256;
    int row = fi >> 4, c8 = (fi & 15) * 8;
    int gn = n0 + row; if (gn >= N_NODES) gn = N_NODES - 1;
    *(uint4*)(sA + row * 136 + c8) = *(const uint4*)(A + (size_t)gn * H + c8);
  }
  __syncthreads();
  MMAcc r;
#pragma unroll
  for (int i = 0; i < 2; ++i)
#pragma unroll
    for (int j = 0; j < 2; ++j) r.a[i][j] = (f32x4){0.f, 0.f, 0.f, 0.f};
#pragma unroll
  for (int q = 0; q < 4; ++q) {
    short8 ah[2];
#pragma unroll
    for (int rt = 0; rt < 2; ++rt)
      ah[rt] = *(const short8*)(sA + (wr * 32 + rt * 16 + m) * 136 + q * 32 + quad * 8);
#pragma unroll
    for (int rt = 0; rt < 2; ++rt)
#pragma unroll
      for (int ct = 0; ct < 2; ++ct)
        r.a[rt][ct] = __builtin_amdgcn_mfma_f32_16x16x32_bf16(ah[rt], bh[q][ct], r.a[rt][ct], 0, 0, 0);
  }
  return r;
}

__device__ __forceinline__ void mm_store_fp8(const MMAcc& r, unsigned char* ht8,
                                             int n0, int c0, int t) {
  int wave = t >> 6, lane = t & 63;
  int wr = wave >> 1, wc = wave & 1;
  int m = lane & 15, quad = (lane >> 4) & 3;
#pragma unroll
  for (int rt = 0; rt < 2; ++rt)
#pragma unroll
    for (int ct = 0; ct < 2; ++ct) {
      int col = c0 + wc * 32 + ct * 16 + m;
#pragma unroll
      for (int rr = 0; rr < 4; ++rr) {
        int gn = n0 + wr * 32 + rt * 16 + quad * 4 + rr;
        if (gn < N_NODES) ht8[(size_t)gn * H + col] = f32_to_fp8(r.a[rt][ct][rr]);
      }
    }
}

__global__ __launch_bounds__(256) void k_mm(const unsigned short* __restrict__ A,
                                            const unsigned short* __restrict__ WhiT,
                                            unsigned char* __restrict__ ht8) {
  __shared__ __align__(16) unsigned short sA[64 * 136];
  int j = blockIdx.x;
  int n0 = (j >> 1) * 64, c0 = (j & 1) * 64;
  MMAcc r = mm_core(A, WhiT, n0, c0, threadIdx.x, sA);
  mm_store_fp8(r, ht8, n0, c0, threadIdx.x);
}

// layer-2 dual GEMM
__global__ __launch_bounds__(256) void k_mmd(const unsigned short* __restrict__ A,
    const unsigned short* __restrict__ WcT, const unsigned short* __restrict__ WrT,
    const float* __restrict__ bias,
    unsigned char* __restrict__ ht8, unsigned short* __restrict__ resb) {
  __shared__ __align__(16) unsigned short sA[64 * 136];
  int t = threadIdx.x;
  int j = blockIdx.x;
  int n0 = (j >> 1) * 64, c0 = (j & 1) * 64;
  int wave = t >> 6, lane = t & 63;
  int wr = wave >> 1, wc = wave & 1;
  int m = lane & 15, quad = (lane >> 4) & 3;
  short8 bhc[4][2], bhr[4][2];
#pragma unroll
  for (int q = 0; q < 4; ++q)
#pragma unroll
    for (int ct = 0; ct < 2; ++ct) {
      int n = c0 + wc * 32 + ct * 16 + m;
      bhc[q][ct] = *(const short8*)(WcT + n * H + q * 32 + quad * 8);
      bhr[q][ct] = *(const short8*)(WrT + n * H + q * 32 + quad * 8);
    }
#pragma unroll
  for (int p = 0; p < 4; ++p) {
    int fi = t + p * 256;
    int row = fi >> 4, c8 = (fi & 15) * 8;
    int gn = n0 + row; if (gn >= N_NODES) gn = N_NODES - 1;
    *(uint4*)(sA + row * 136 + c8) = *(const uint4*)(A + (size_t)gn * H + c8);
  }
  __syncthreads();
  f32x4 accC[2][2], accR[2][2];
#pragma unroll
  for (int i = 0; i < 2; ++i)
#pragma unroll
    for (int jj = 0; jj < 2; ++jj) {
      accC[i][jj] = (f32x4){0.f, 0.f, 0.f, 0.f};
      accR[i][jj] = (f32x4){0.f, 0.f, 0.f, 0.f};
    }
#pragma unroll
  for (int q = 0; q < 4; ++q) {
    short8 ah[2];
#pragma unroll
    for (int rt = 0; rt < 2; ++rt)
      ah[rt] = *(const short8*)(sA + (wr * 32 + rt * 16 + m) * 136 + q * 32 + quad * 8);
#pragma unroll
    for (int rt = 0; rt < 2; ++rt)
#pragma unroll
      for (int ct = 0; ct < 2; ++ct) {
        accC[rt][ct] = __builtin_amdgcn_mfma_f32_16x16x32_bf16(ah[rt], bhc[q][ct], accC[rt][ct], 0, 0, 0);
        accR[rt][ct] = __builtin_amdgcn_mfma_f32_16x16x32_bf16(ah[rt], bhr[q][ct], accR[rt][ct], 0, 0, 0);
      }
  }
#pragma unroll
  for (int rt = 0; rt < 2; ++rt)
#pragma unroll
    for (int ct = 0; ct < 2; ++ct) {
      int col = c0 + wc * 32 + ct * 16 + m;
      float bv = bias[col];
#pragma unroll
      for (int rr = 0; rr < 4; ++rr) {
        int gn = n0 + wr * 32 + rt * 16 + quad * 4 + rr;
        if (gn < N_NODES) {
          ht8[(size_t)gn * H + col]  = f32_to_fp8(accC[rt][ct][rr]);
          resb[(size_t)gn * H + col] = f2bf(accR[rt][ct][rr] + bv);
        }
      }
    }
}

// ---------------- aggregate(fp8 ht) + bias + LN + relu + residual(bf16) ----------------
// r14 layout (4 groups x 16 lanes, uint2 gathers), 32-edge rounds with 8
// uint2 loads in flight. r16: added 16-slot (4-deep) tail round — degrees
// are ~Poisson(16), so 57% of nodes have cnt<=16 but paid a full 32-slot
// round of decode+FMA (wasted slots fma zeros). Expected slots 32 -> ~23.
template <int NJ>
__device__ __forceinline__ void agg_round(const unsigned char* __restrict__ hb,
                                          int e0, int grp, int s, float w,
                                          float* acc) {
  uint2 uu[NJ]; float ww[NJ];
#pragma unroll
  for (int jj = 0; jj < NJ; ++jj) {
    int idx = e0 + jj * 4 + grp;   // < 64 always
    int ss = __shfl(s, idx, 64);
    ww[jj] = __shfl(w, idx, 64);
    uu[jj] = *(const uint2*)(hb + (size_t)ss * 128);
  }
#pragma unroll
  for (int jj = 0; jj < NJ; ++jj) {
    float we = ww[jj];
    fv2 a = fp8x2<false>(uu[jj].x), b = fp8x2<true>(uu[jj].x);
    fv2 c = fp8x2<false>(uu[jj].y), d2 = fp8x2<true>(uu[jj].y);
    acc[0] = fmaf(we, a.x, acc[0]);
    acc[1] = fmaf(we, a.y, acc[1]);
    acc[2] = fmaf(we, b.x, acc[2]);
    acc[3] = fmaf(we, b.y, acc[3]);
    acc[4] = fmaf(we, c.x, acc[4]);
    acc[5] = fmaf(we, c.y, acc[5]);
    acc[6] = fmaf(we, d2.x, acc[6]);
    acc[7] = fmaf(we, d2.y, acc[7]);
  }
}

__global__ __launch_bounds__(256) void k_agg(
    const unsigned char* __restrict__ ht8, const unsigned short* __restrict__ res,
    const float* __restrict__ dinv, const int* __restrict__ offs,
    const int* __restrict__ parts, const int* __restrict__ degT,
    const unsigned* __restrict__ csr,
    const float* __restrict__ bias, const float* __restrict__ lng,
    const float* __restrict__ lnb, unsigned short* __restrict__ hout) {
  int wid = threadIdx.x >> 6, lane = threadIdx.x & 63;
  int node = blockIdx.x * 4 + wid;
  if (node >= N_NODES) return;
  int grp = lane >> 4, fl = lane & 15;
  int start = offs[node] + parts[node >> 8], cnt = degT[node];
  float di = dinv[node];
  const unsigned char* hb = ht8 + fl * 8;
  float acc[8];
  {
    uint2 u = *(const uint2*)(hb + (size_t)node * 128);
    float sw = (grp == 0) ? di * di : 0.f;
    fv2 a = fp8x2<false>(u.x), b = fp8x2<true>(u.x);
    fv2 c = fp8x2<false>(u.y), d2 = fp8x2<true>(u.y);
    acc[0] = sw * a.x; acc[1] = sw * a.y;
    acc[2] = sw * b.x; acc[3] = sw * b.y;
    acc[4] = sw * c.x; acc[5] = sw * c.y;
    acc[6] = sw * d2.x; acc[7] = sw * d2.y;
  }
  float ddq = di * (1.f / 32767.f);
  for (int b0 = 0; b0 < cnt; b0 += 64) {
    int mm_ = min(64, cnt - b0);
    int s = 0; float w = 0.f;
    if (lane < mm_) {
      unsigned ev = csr[start + b0 + lane];
      s = (int)(ev >> 15);
      w = (float)(ev & 32767u) * ddq;
    }
    int e0 = 0;
    for (; e0 + 32 <= mm_; e0 += 32) agg_round<8>(hb, e0, grp, s, w, acc);
    int rem = mm_ - e0;
    if (rem > 16)      agg_round<8>(hb, e0, grp, s, w, acc);
    else if (rem > 0)  agg_round<4>(hb, e0, grp, s, w, acc);
  }
#pragma unroll
  for (int j = 0; j < 8; ++j) {
    acc[j] += __shfl_xor(acc[j], 16, 64);
    acc[j] += __shfl_xor(acc[j], 32, 64);
  }
  float4 b0v = *(const float4*)(bias + fl * 8);
  float4 b1v = *(const float4*)(bias + fl * 8 + 4);
  acc[0] += b0v.x; acc[1] += b0v.y; acc[2] += b0v.z; acc[3] += b0v.w;
  acc[4] += b1v.x; acc[5] += b1v.y; acc[6] += b1v.z; acc[7] += b1v.w;
  float sl = ((acc[0] + acc[1]) + (acc[2] + acc[3])) +
             ((acc[4] + acc[5]) + (acc[6] + acc[7]));
#pragma unroll
  for (int mk = 1; mk <= 8; mk <<= 1) sl += __shfl_xor(sl, mk, 64);
  float mu = sl * (1.f / 128.f);
  float d[8];
  float vl = 0.f;
#pragma unroll
  for (int j = 0; j < 8; ++j) { d[j] = acc[j] - mu; vl = fmaf(d[j], d[j], vl); }
#pragma unroll
  for (int mk = 1; mk <= 8; mk <<= 1) vl += __shfl_xor(vl, mk, 64);
  float rs = rsqrtf(vl * (1.f / 128.f) + EPS);
  if (grp == 0) {
    float4 g0 = *(const float4*)(lng + fl * 8);
    float4 g1 = *(const float4*)(lng + fl * 8 + 4);
    float4 be0 = *(const float4*)(lnb + fl * 8);
    float4 be1 = *(const float4*)(lnb + fl * 8 + 4);
    uint4 rv = *(const uint4*)(res + (size_t)node * 128 + fl * 8);
    float o0 = fmaxf(fmaf(d[0] * rs, g0.x, be0.x), 0.f) + bflo(rv.x);
    float o1 = fmaxf(fmaf(d[1] * rs, g0.y, be0.y), 0.f) + bfhi(rv.x);
    float o2 = fmaxf(fmaf(d[2] * rs, g0.z, be0.z), 0.f) + bflo(rv.y);
    float o3 = fmaxf(fmaf(d[3] * rs, g0.w, be0.w), 0.f) + bfhi(rv.y);
    float o4 = fmaxf(fmaf(d[4] * rs, g1.x, be1.x), 0.f) + bflo(rv.z);
    float o5 = fmaxf(fmaf(d[5] * rs, g1.y, be1.y), 0.f) + bfhi(rv.z);
    float o6 = fmaxf(fmaf(d[6] * rs, g1.z, be1.z), 0.f) + bflo(rv.w);
    float o7 = fmaxf(fmaf(d[7] * rs, g1.w, be1.w), 0.f) + bfhi(rv.w);
    uint4 ov;
    ov.x = pack2(o0, o1); ov.y = pack2(o2, o3);
    ov.z = pack2(o4, o5); ov.w = pack2(o6, o7);
    *(uint4*)(hout + (size_t)node * 128 + fl * 8) = ov;
  }
}

// ---------------- mean pool (bf16 h, vectorized uint4 loads) ----------------
__global__ __launch_bounds__(256) void k_pool(const unsigned short* __restrict__ h,
                                              float* __restrict__ pool) {
  __shared__ float colsum[128];
  int t = threadIdx.x;
  if (t < 128) colsum[t] = 0.f;
  __syncthreads();
  int lr = t >> 4, seg = t & 15;   // 16 rows/pass, 16 x uint4 per row
  float acc[8] = {0.f, 0.f, 0.f, 0.f, 0.f, 0.f, 0.f, 0.f};
  for (int n = blockIdx.x * 16 + lr; n < N_NODES; n += gridDim.x * 16) {
    uint4 u = *(const uint4*)(h + (size_t)n * H + seg * 8);
    acc[0] += bflo(u.x); acc[1] += bfhi(u.x);
    acc[2] += bflo(u.y); acc[3] += bfhi(u.y);
    acc[4] += bflo(u.z); acc[5] += bfhi(u.z);
    acc[6] += bflo(u.w); acc[7] += bfhi(u.w);
  }
#pragma unroll
  for (int j = 0; j < 8; ++j) atomicAdd(&colsum[seg * 8 + j], acc[j]);
  __syncthreads();
  if (t < 128) atomicAdd(&pool[t], colsum[t]);
}

// ---------------- head ----------------
__global__ void k_head(const float* __restrict__ pool, const float* __restrict__ Wfc1,
                       const float* __restrict__ bfc1, const float* __restrict__ g,
                       const float* __restrict__ bb, const float* __restrict__ Wfc2,
                       const float* __restrict__ bfc2, float* __restrict__ out) {
  __shared__ float sm[128], s1[128], stats[2];
  int t = threadIdx.x;
  if (t < 128) sm[t] = pool[t] * (1.f / (float)N_NODES);
  __syncthreads();
  if (t < 128) {
    float a = bfc1[t];
    for (int k = 0; k < 128; ++k) a = fmaf(sm[k], Wfc1[k * 128 + t], a);
    s1[t] = a;
  }
  __syncthreads();
  if (t == 0) {
    float mu = 0.f;
    for (int k = 0; k < 128; ++k) mu += s1[k];
    mu *= (1.f / 128.f);
    float var = 0.f;
    for (int k = 0; k < 128; ++k) { float d = s1[k] - mu; var += d * d; }
    var *= (1.f / 128.f);
    stats[0] = mu; stats[1] = rsqrtf(var + EPS);
  }
  __syncthreads();
  if (t < 128) s1[t] = fmaxf((s1[t] - stats[0]) * stats[1] * g[t] + bb[t], 0.f);
  __syncthreads();
  if (t < OUT_F) {
    float a = bfc2[t];
    for (int k = 0; k < 128; ++k) a = fmaf(s1[k], Wfc2[k * OUT_F + t], a);
    out[t] = a;
  }
}

extern "C" void kernel_launch(void* const* d_in, const int* in_sizes, int n_in,
                              void* d_out, int out_size, void* d_ws, size_t ws_size,
                              hipStream_t stream) {
  const float* x      = (const float*)d_in[0];
  const int*   ei     = (const int*)d_in[1];
  const float* W_emb  = (const float*)d_in[2];
  const float* b_emb  = (const float*)d_in[3];
  const float* W_conv = (const float*)d_in[4];
  const float* b_conv = (const float*)d_in[5];
  const float* ln_g   = (const float*)d_in[6];
  const float* ln_b   = (const float*)d_in[7];
  const float* W_res  = (const float*)d_in[8];
  const float* b_res  = (const float*)d_in[9];
  const float* W_fc1  = (const float*)d_in[10];
  const float* b_fc1  = (const float*)d_in[11];
  const float* fcn_g  = (const float*)d_in[12];
  const float* fcn_b  = (const float*)d_in[13];
  const float* W_fc2  = (const float*)d_in[14];
  const float* b_fc2  = (const float*)d_in[15];
  float* out = (float*)d_out;

  char* p = (char*)d_ws;
  auto take = [&](size_t bytes) {
    char* r = p; p += (bytes + 255) & ~(size_t)255; return r;
  };
  unsigned short* bufA = (unsigned short*)take((size_t)N_NODES * H * 2);
  unsigned short* bufB = (unsigned short*)take((size_t)N_NODES * H * 2);
  unsigned short* bufC = (unsigned short*)take((size_t)N_NODES * H * 2);
  unsigned char*  ht8  = (unsigned char*)take((size_t)N_NODES * H);
  unsigned short* whiT = (unsigned short*)take((size_t)5 * H * H * 2);
  int*   deg8 = (int*)take((size_t)NXCD * N_NODES * 4);
  int*   degT = (int*)take(N_NODES * 4);
  int*   xoff = (int*)take((size_t)NXCD * N_NODES * 4);
  int*   parts= (int*)take(512 * 4);
  float* dinv = (float*)take(N_NODES * 4);
  unsigned short* ranks16 = (unsigned short*)take((size_t)NEDGES * 2);
  unsigned* csr = (unsigned*)take((size_t)NEDGES * 4);
  float* pool = (float*)take(128 * 4);

  (void)hipMemsetAsync(deg8, 0, (size_t)NXCD * N_NODES * 4, stream);
  (void)hipMemsetAsync(pool, 0, 128 * 4, stream);

  k_ws<<<WS_BLKS, 256, 0, stream>>>(W_conv, W_res, whiT);
  k_pre3<<<PRE3_BLKS, 256, 0, stream>>>(ei, deg8, ranks16, x, W_emb, b_emb, bufA,
                                        whiT + 0 * H * H, ht8);
  k_scan_a<<<NPARTS, 256, 0, stream>>>(deg8, degT, xoff, parts, dinv);
  k_scan_b<<<1, 512, 0, stream>>>(parts, NPARTS);
  k_fill<<<FILL_BLKS, 256, 0, stream>>>(ei, ranks16, xoff, parts, dinv, csr);

  int aggg = (N_NODES + 3) / 4;
  // L0: res=h0=A -> h1=C
  k_agg<<<aggg, 256, 0, stream>>>(ht8, bufA, dinv, xoff, parts, degT, csr,
                                  b_conv + 0 * H, ln_g + 0 * H, ln_b + 0 * H, bufC);
  // L1: h1=C -> ht8 -> h2=A (res=C)
  k_mm<<<MM_BLKS, 256, 0, stream>>>(bufC, whiT + 1 * H * H, ht8);
  k_agg<<<aggg, 256, 0, stream>>>(ht8, bufC, dinv, xoff, parts, degT, csr,
                                  b_conv + 1 * H, ln_g + 1 * H, ln_b + 1 * H, bufA);
  // L2: h2=A; dual: ht8=A@W2, B=bf16(A@Wres+bres); agg -> h3=C (res=B)
  k_mmd<<<MM_BLKS, 256, 0, stream>>>(bufA, whiT + 2 * H * H, whiT + 4 * H * H,
                                     b_res, ht8, bufB);
  k_agg<<<aggg, 256, 0, stream>>>(ht8, bufB, dinv, xoff, parts, degT, csr,
                                  b_conv + 2 * H, ln_g + 2 * H, ln_b + 2 * H, bufC);
  // L3: h3=C -> ht8 -> h4=A (res=C)
  k_mm<<<MM_BLKS, 256, 0, stream>>>(bufC, whiT + 3 * H * H, ht8);
  k_agg<<<aggg, 256, 0, stream>>>(ht8, bufC, dinv, xoff, parts, degT, csr,
                                  b_conv + 3 * H, ln_g + 3 * H, ln_b + 3 * H, bufA);

  k_pool<<<256, 256, 0, stream>>>(bufA, pool);
  k_head<<<1, 256, 0, stream>>>(pool, W_fc1, b_fc1, fcn_g, fcn_b,
                                W_fc2, b_fc2, out);
}

// Round 2
// 558.791 us; speedup vs baseline: 1.0653x; 1.0653x over previous
//
#include <hip/hip_runtime.h>

constexpr int N_NODES = 100000;
constexpr int F_IN    = 32;
constexpr int H       = 128;
constexpr int OUT_F   = 200;
constexpr int NEDGES  = 1600000;
constexpr float EPS   = 1e-5f;
constexpr int NXCD    = 8;

constexpr int HIST8_BLKS = (NEDGES / 8 + 255) / 256;  // 782
constexpr int WS_BLKS    = 80;                        // 5*128*128/1024
constexpr int NPARTS     = (N_NODES + 255) / 256;     // 391
constexpr int FILL_BLKS  = (NEDGES / 4 + 255) / 256;  // 1563
constexpr int TILE_BLKS  = (N_NODES + 63) / 64;       // 1563
constexpr int PRE3_BLKS  = HIST8_BLKS + TILE_BLKS;    // 2345 (1:2 interleave)
constexpr int MM_BLKS    = TILE_BLKS * 2;             // 3126 (64r x 64c tiles)
constexpr int AGG_BLKS   = (N_NODES + 7) / 8;         // 12500 (512 thr, 8 nodes)

typedef __attribute__((ext_vector_type(8))) short  short8;
typedef __attribute__((ext_vector_type(4))) float  f32x4;
typedef __attribute__((ext_vector_type(2))) float  fv2;

__device__ __forceinline__ void fma4(float4& a, float s, const float4& w) {
  a.x = fmaf(s, w.x, a.x); a.y = fmaf(s, w.y, a.y);
  a.z = fmaf(s, w.z, a.z); a.w = fmaf(s, w.w, a.w);
}

__device__ __forceinline__ unsigned short f2bf(float f) {  // RNE
  union { float f; unsigned u; } v; v.f = f;
  unsigned r = v.u + 0x7fffu + ((v.u >> 16) & 1u);
  return (unsigned short)(r >> 16);
}
__device__ __forceinline__ float bf2f(unsigned short s) {
  union { unsigned u; float f; } v; v.u = ((unsigned)s) << 16;
  return v.f;
}
__device__ __forceinline__ float bflo(unsigned u) { return __uint_as_float(u << 16); }
__device__ __forceinline__ float bfhi(unsigned u) { return __uint_as_float(u & 0xffff0000u); }
__device__ __forceinline__ unsigned pack2(float lo, float hi) {
  return (unsigned)f2bf(lo) | ((unsigned)f2bf(hi) << 16);
}
__device__ __forceinline__ void st_bf4(unsigned short* p, float4 v) {
  uint2 o; o.x = pack2(v.x, v.y); o.y = pack2(v.z, v.w);
  *(uint2*)p = o;
}

// ---------------- fp8 e4m3fn helpers ----------------
#if __has_builtin(__builtin_amdgcn_cvt_pk_f32_fp8) && __has_builtin(__builtin_amdgcn_cvt_pk_fp8_f32)
#define HAVE_FP8_CVT 1
#endif

#ifndef HAVE_FP8_CVT
__device__ __forceinline__ float fp8_dec1(unsigned b) {
  unsigned s = (b >> 7) & 1u, E = (b >> 3) & 15u, m = b & 7u;
  float v;
  if (E) {
    union { unsigned u; float f; } t;
    t.u = (s << 31) | ((E + 120u) << 23) | (m << 20);
    v = t.f;
  } else {
    v = (s ? -1.f : 1.f) * (float)m * 0.001953125f;
  }
  return v;
}
#endif

template <bool HI>
__device__ __forceinline__ fv2 fp8x2(unsigned u) {
#ifdef HAVE_FP8_CVT
  return __builtin_amdgcn_cvt_pk_f32_fp8((int)u, HI);
#else
  unsigned p = HI ? (u >> 16) : u;
  fv2 r; r.x = fp8_dec1(p & 0xffu); r.y = fp8_dec1((p >> 8) & 0xffu);
  return r;
#endif
}

__device__ __forceinline__ unsigned char f32_to_fp8(float f) {
#ifdef HAVE_FP8_CVT
  return (unsigned char)(__builtin_amdgcn_cvt_pk_fp8_f32(f, f, 0, false) & 0xff);
#else
  union { float f; unsigned u; } t; t.f = f;
  unsigned s = t.u >> 31;
  float a = fabsf(f);
  if (a > 448.f) a = 448.f;
  t.f = a;
  int e = (int)((t.u >> 23) & 0xff) - 127;
  unsigned char r;
  if (a == 0.f) {
    r = 0;
  } else if (e >= -6) {
    unsigned m = t.u & 0x7fffffu;
    unsigned keep = m >> 20, rest = m & 0xfffffu;
    keep += (rest > 0x80000u) || (rest == 0x80000u && (keep & 1u));
    int E = e + 7;
    if (keep == 8u) { keep = 0u; E += 1; }
    if (E >= 16) { E = 15; keep = 6u; }
    r = (unsigned char)((E << 3) | keep);
  } else {
    int mi = (int)(a * 512.f + 0.5f);
    r = (mi > 7) ? (unsigned char)(1u << 3) : (unsigned char)mi;
  }
  return (unsigned char)(r | (s << 7));
#endif
}

// ---------------- k_ws: W -> bf16 transposed ----------------
__global__ void k_ws(const float* __restrict__ W_conv,
                     const float* __restrict__ W_res,
                     unsigned short* __restrict__ whiT) {
  int base = blockIdx.x * 1024;
#pragma unroll
  for (int j = 0; j < 4; ++j) {
    int idx = base + j * 256 + threadIdx.x;
    if (idx < 5 * H * H) {
      int m = idx >> 14, rr = idx & 16383;
      int k = rr >> 7, n = rr & 127;
      const float* src = (m < 4) ? (W_conv + m * H * H) : W_res;
      whiT[m * H * H + n * H + k] = f2bf(src[k * H + n]);
    }
  }
}

// mm from LDS tile: 64 rows x 128 cols, wave = 32r x 64c (B frags hoisted)
__device__ __forceinline__ void mm_lds_fp8(const unsigned short* sA,
                                           const unsigned short* __restrict__ WT,
                                           int n0, int t,
                                           unsigned char* __restrict__ htOut) {
  int wave = t >> 6, lane = t & 63;
  int wr = wave >> 1, wc = wave & 1;
  int m = lane & 15, quad = (lane >> 4) & 3;
  short8 bh[4][4];
#pragma unroll
  for (int q = 0; q < 4; ++q)
#pragma unroll
    for (int ct = 0; ct < 4; ++ct) {
      int n = wc * 64 + ct * 16 + m;
      bh[q][ct] = *(const short8*)(WT + n * H + q * 32 + quad * 8);
    }
  f32x4 acc[2][4];
#pragma unroll
  for (int i = 0; i < 2; ++i)
#pragma unroll
    for (int j = 0; j < 4; ++j) acc[i][j] = (f32x4){0.f, 0.f, 0.f, 0.f};
#pragma unroll
  for (int q = 0; q < 4; ++q) {
    short8 ah[2];
#pragma unroll
    for (int rt = 0; rt < 2; ++rt)
      ah[rt] = *(const short8*)(sA + (wr * 32 + rt * 16 + m) * 136 + q * 32 + quad * 8);
#pragma unroll
    for (int rt = 0; rt < 2; ++rt)
#pragma unroll
      for (int ct = 0; ct < 4; ++ct)
        acc[rt][ct] = __builtin_amdgcn_mfma_f32_16x16x32_bf16(ah[rt], bh[q][ct], acc[rt][ct], 0, 0, 0);
  }
#pragma unroll
  for (int rt = 0; rt < 2; ++rt)
#pragma unroll
    for (int ct = 0; ct < 4; ++ct) {
      int col = wc * 64 + ct * 16 + m;
#pragma unroll
      for (int rr = 0; rr < 4; ++rr) {
        int gn = n0 + wr * 32 + rt * 16 + quad * 4 + rr;
        if (gn < N_NODES) htOut[(size_t)gn * H + col] = f32_to_fp8(acc[rt][ct][rr]);
      }
    }
}

// ---------------- k_pre3: hist | (embed 64-node tile -> LDS -> mm W0), 1:2 ----------------
// r16: histogram privatized per physical XCD (HW_REG_XCC_ID) with
// WORKGROUP-scope atomic RMW (drops sc1; RMW runs in the local XCD L2;
// per-slice atomicity holds since each slice is touched by one XCD only).
// This removed k_pre3 from the top-5 (device-scope atomics were ~8/cycle
// at the shared coherence point = the whole 80us). ranks=(xcd<<8)|rank.
__global__ __launch_bounds__(256) void k_pre3(
    const int* __restrict__ ei, int* __restrict__ deg8,
    unsigned short* __restrict__ ranks16,
    const float* __restrict__ x, const float* __restrict__ W_emb,
    const float* __restrict__ b_emb, unsigned short* __restrict__ h,
    const unsigned short* __restrict__ W0T, unsigned char* __restrict__ ht8) {
  __shared__ __align__(16) char smem[25600];
  int t = threadIdx.x;
  int id = blockIdx.x;
  int q3 = id / 3, r3 = id - q3 * 3;
  if (r3 == 0) {
    unsigned xcd;
    asm("s_getreg_b32 %0, hwreg(HW_REG_XCC_ID)" : "=s"(xcd));
    xcd &= 7u;
    int* dslice = deg8 + (size_t)xcd * N_NODES;
    unsigned hx = xcd << 8;
    int i = q3 * 256 + t;
    if (i < NEDGES / 8) {
      int4 a = *(const int4*)(ei + NEDGES + 8 * i);
      int4 b = *(const int4*)(ei + NEDGES + 8 * i + 4);
      union { unsigned short u16[8]; uint4 u4; } rr;
      rr.u16[0] = (unsigned short)(hx | (unsigned)__hip_atomic_fetch_add(dslice + a.x, 1, __ATOMIC_RELAXED, __HIP_MEMORY_SCOPE_WORKGROUP));
      rr.u16[1] = (unsigned short)(hx | (unsigned)__hip_atomic_fetch_add(dslice + a.y, 1, __ATOMIC_RELAXED, __HIP_MEMORY_SCOPE_WORKGROUP));
      rr.u16[2] = (unsigned short)(hx | (unsigned)__hip_atomic_fetch_add(dslice + a.z, 1, __ATOMIC_RELAXED, __HIP_MEMORY_SCOPE_WORKGROUP));
      rr.u16[3] = (unsigned short)(hx | (unsigned)__hip_atomic_fetch_add(dslice + a.w, 1, __ATOMIC_RELAXED, __HIP_MEMORY_SCOPE_WORKGROUP));
      rr.u16[4] = (unsigned short)(hx | (unsigned)__hip_atomic_fetch_add(dslice + b.x, 1, __ATOMIC_RELAXED, __HIP_MEMORY_SCOPE_WORKGROUP));
      rr.u16[5] = (unsigned short)(hx | (unsigned)__hip_atomic_fetch_add(dslice + b.y, 1, __ATOMIC_RELAXED, __HIP_MEMORY_SCOPE_WORKGROUP));
      rr.u16[6] = (unsigned short)(hx | (unsigned)__hip_atomic_fetch_add(dslice + b.z, 1, __ATOMIC_RELAXED, __HIP_MEMORY_SCOPE_WORKGROUP));
      rr.u16[7] = (unsigned short)(hx | (unsigned)__hip_atomic_fetch_add(dslice + b.w, 1, __ATOMIC_RELAXED, __HIP_MEMORY_SCOPE_WORKGROUP));
      ((uint4*)ranks16)[i] = rr.u4;
    }
  } else {
    int j = q3 * 2 + (r3 - 1);
    int n0 = j * 64;
    float* sW = (float*)smem;
    float* sX = sW + 4096;
    unsigned short* sH = (unsigned short*)smem;
#pragma unroll
    for (int p = 0; p < 4; ++p)
      ((float4*)sW)[t + p * 256] = ((const float4*)W_emb)[t + p * 256];
#pragma unroll
    for (int p = 0; p < 2; ++p) {
      int fi = t * 2 + p;
      int row = fi >> 3, k4 = (fi & 7) * 4;
      int gn = n0 + row; if (gn >= N_NODES) gn = N_NODES - 1;
      *(float4*)(sX + row * 36 + k4) = *(const float4*)(x + (size_t)gn * F_IN + k4);
    }
    __syncthreads();
    // conflict-free sW reads: col0 = (t&3)*4 -> banks {0,4,8,12}(+16i)
    int nr = t >> 2, col0 = (t & 3) * 4;
    float4 acc[8];
#pragma unroll
    for (int i = 0; i < 8; ++i) acc[i] = make_float4(0.f, 0.f, 0.f, 0.f);
#pragma unroll 4
    for (int k = 0; k < F_IN; ++k) {
      float xv = sX[nr * 36 + k];
      const float* wp = sW + k * H + col0;
#pragma unroll
      for (int i = 0; i < 8; ++i) fma4(acc[i], xv, *(const float4*)(wp + i * 16));
    }
#pragma unroll
    for (int i = 0; i < 8; ++i) {
      float4 bv = *(const float4*)(b_emb + col0 + i * 16);
      acc[i].x += bv.x; acc[i].y += bv.y; acc[i].z += bv.z; acc[i].w += bv.w;
    }
    __syncthreads();  // done reading sW/sX; reuse as sH
    int node = n0 + nr;
    unsigned short* hr = h + (size_t)node * H + col0;
#pragma unroll
    for (int i = 0; i < 8; ++i) {
      st_bf4(sH + nr * 136 + col0 + i * 16, acc[i]);
      if (node < N_NODES) st_bf4(hr + i * 16, acc[i]);
    }
    __syncthreads();
    mm_lds_fp8(sH, W0T, n0, t, ht8);
  }
}

// ---------------- scans ----------------
// r17: fold 8 per-XCD slices into total degree + PACKED per-node slice
// prefixes (xp8: 8 bytes/node, valid since total deg < 256 — the u8-rank
// scheme already assumes this). r16's 3.2MB xoff killed k_fill locality
// (per-entry reuse 16x -> 2x); offs(400KB)+xp8(800KB) are L2-resident.
__global__ void k_scan_a(const int* __restrict__ deg8, int* __restrict__ degT,
                         int* __restrict__ offs, uint2* __restrict__ xp8,
                         int* __restrict__ parts, float* __restrict__ dinv) {
  __shared__ int s[256];
  int i = blockIdx.x * 256 + threadIdx.x;
  int d[NXCD];
  int tot = 0;
#pragma unroll
  for (int c = 0; c < NXCD; ++c) {
    d[c] = (i < N_NODES) ? deg8[(size_t)c * N_NODES + i] : 0;
    tot += d[c];
  }
  s[threadIdx.x] = tot;
  __syncthreads();
#pragma unroll
  for (int off = 1; off < 256; off <<= 1) {
    int v = (threadIdx.x >= off) ? s[threadIdx.x - off] : 0;
    __syncthreads();
    s[threadIdx.x] += v;
    __syncthreads();
  }
  if (i < N_NODES) {
    offs[i] = s[threadIdx.x] - tot;   // block-local exclusive
    degT[i] = tot;
    dinv[i] = rsqrtf((float)(tot + 1));
    unsigned p = 0, lo = 0, hi = 0;
#pragma unroll
    for (int c = 0; c < 4; ++c) { lo |= (p & 255u) << (8 * c); p += (unsigned)d[c]; }
#pragma unroll
    for (int c = 4; c < 8; ++c) { hi |= (p & 255u) << (8 * (c - 4)); p += (unsigned)d[c]; }
    uint2 xp; xp.x = lo; xp.y = hi;
    xp8[i] = xp;
  }
  if (threadIdx.x == 255) parts[blockIdx.x] = s[255];
}

__global__ void k_scan_b(int* __restrict__ parts, int nparts) {
  __shared__ int s[512];
  int t = threadIdx.x;
  int d = (t < nparts) ? parts[t] : 0;
  s[t] = d;
  __syncthreads();
#pragma unroll
  for (int off = 1; off < 512; off <<= 1) {
    int v = (t >= off) ? s[t - off] : 0;
    __syncthreads();
    s[t] += v;
    __syncthreads();
  }
  if (t < nparts) parts[t] = s[t] - d;
}

// ---------------- k_fill ----------------
__global__ __launch_bounds__(256) void k_fill(
    const int* __restrict__ ei, const unsigned short* __restrict__ ranks16,
    const int* __restrict__ offs, const uint2* __restrict__ xp8,
    const int* __restrict__ parts,
    const float* __restrict__ dinv, unsigned* __restrict__ csr) {
  int i = blockIdx.x * 256 + threadIdx.x;
  if (i < NEDGES / 4) {
    int4 s4 = *(const int4*)(ei + 4 * i);
    int4 d4 = *(const int4*)(ei + NEDGES + 4 * i);
    uint2 rv = ((const uint2*)ranks16)[i];
    unsigned r0 = rv.x & 0xffffu, r1 = rv.x >> 16;
    unsigned r2 = rv.y & 0xffffu, r3 = rv.y >> 16;
    auto pos = [&](int dst, unsigned r) {
      uint2 xp = xp8[dst];
      unsigned xc = r >> 8;
      unsigned pre = ((xc < 4u) ? (xp.x >> (xc * 8u)) : (xp.y >> ((xc - 4u) * 8u))) & 255u;
      return offs[dst] + parts[dst >> 8] + (int)pre + (int)(r & 255u);
    };
    int p0 = pos(d4.x, r0);
    int p1 = pos(d4.y, r1);
    int p2 = pos(d4.z, r2);
    int p3 = pos(d4.w, r3);
    csr[p0] = ((unsigned)s4.x << 15) | (unsigned)(dinv[s4.x] * 32767.f + 0.5f);
    csr[p1] = ((unsigned)s4.y << 15) | (unsigned)(dinv[s4.y] * 32767.f + 0.5f);
    csr[p2] = ((unsigned)s4.z << 15) | (unsigned)(dinv[s4.z] * 32767.f + 0.5f);
    csr[p3] = ((unsigned)s4.w << 15) | (unsigned)(dinv[s4.w] * 32767.f + 0.5f);
  }
}

// ---------------- mm core for layers 1-3 (global A) ----------------
struct MMAcc { f32x4 a[2][2]; };

__device__ __forceinline__ MMAcc mm_core(const unsigned short* __restrict__ A,
                                         const unsigned short* __restrict__ WhiT,
                                         int n0, int c0, int t,
                                         unsigned short* sA) {
  int wave = t >> 6, lane = t & 63;
  int wr = wave >> 1, wc = wave & 1;
  int m = lane & 15, quad = (lane >> 4) & 3;
  short8 bh[4][2];
#pragma unroll
  for (int q = 0; q < 4; ++q)
#pragma unroll
    for (int ct = 0; ct < 2; ++ct) {
      int n = c0 + wc * 32 + ct * 16 + m;
      bh[q][ct] = *(const short8*)(WhiT + n * H + q * 32 + quad * 8);
    }
#pragma unroll
  for (int p = 0; p < 4; ++p) {
    int fi = t + p * 256;
    int row = fi >> 4, c8 = (fi & 15) * 8;
    int gn = n0 + row; if (gn >= N_NODES) gn = N_NODES - 1;
    *(uint4*)(sA + row * 136 + c8) = *(const uint4*)(A + (size_t)gn * H + c8);
  }
  __syncthreads();
  MMAcc r;
#pragma unroll
  for (int i = 0; i < 2; ++i)
#pragma unroll
    for (int j = 0; j < 2; ++j) r.a[i][j] = (f32x4){0.f, 0.f, 0.f, 0.f};
#pragma unroll
  for (int q = 0; q < 4; ++q) {
    short8 ah[2];
#pragma unroll
    for (int rt = 0; rt < 2; ++rt)
      ah[rt] = *(const short8*)(sA + (wr * 32 + rt * 16 + m) * 136 + q * 32 + quad * 8);
#pragma unroll
    for (int rt = 0; rt < 2; ++rt)
#pragma unroll
      for (int ct = 0; ct < 2; ++ct)
        r.a[rt][ct] = __builtin_amdgcn_mfma_f32_16x16x32_bf16(ah[rt], bh[q][ct], r.a[rt][ct], 0, 0, 0);
  }
  return r;
}

__device__ __forceinline__ void mm_store_fp8(const MMAcc& r, unsigned char* ht8,
                                             int n0, int c0, int t) {
  int wave = t >> 6, lane = t & 63;
  int wr = wave >> 1, wc = wave & 1;
  int m = lane & 15, quad = (lane >> 4) & 3;
#pragma unroll
  for (int rt = 0; rt < 2; ++rt)
#pragma unroll
    for (int ct = 0; ct < 2; ++ct) {
      int col = c0 + wc * 32 + ct * 16 + m;
#pragma unroll
      for (int rr = 0; rr < 4; ++rr) {
        int gn = n0 + wr * 32 + rt * 16 + quad * 4 + rr;
        if (gn < N_NODES) ht8[(size_t)gn * H + col] = f32_to_fp8(r.a[rt][ct][rr]);
      }
    }
}

__global__ __launch_bounds__(256) void k_mm(const unsigned short* __restrict__ A,
                                            const unsigned short* __restrict__ WhiT,
                                            unsigned char* __restrict__ ht8) {
  __shared__ __align__(16) unsigned short sA[64 * 136];
  int j = blockIdx.x;
  int n0 = (j >> 1) * 64, c0 = (j & 1) * 64;
  MMAcc r = mm_core(A, WhiT, n0, c0, threadIdx.x, sA);
  mm_store_fp8(r, ht8, n0, c0, threadIdx.x);
}

// layer-2 dual GEMM
__global__ __launch_bounds__(256) void k_mmd(const unsigned short* __restrict__ A,
    const unsigned short* __restrict__ WcT, const unsigned short* __restrict__ WrT,
    const float* __restrict__ bias,
    unsigned char* __restrict__ ht8, unsigned short* __restrict__ resb) {
  __shared__ __align__(16) unsigned short sA[64 * 136];
  int t = threadIdx.x;
  int j = blockIdx.x;
  int n0 = (j >> 1) * 64, c0 = (j & 1) * 64;
  int wave = t >> 6, lane = t & 63;
  int wr = wave >> 1, wc = wave & 1;
  int m = lane & 15, quad = (lane >> 4) & 3;
  short8 bhc[4][2], bhr[4][2];
#pragma unroll
  for (int q = 0; q < 4; ++q)
#pragma unroll
    for (int ct = 0; ct < 2; ++ct) {
      int n = c0 + wc * 32 + ct * 16 + m;
      bhc[q][ct] = *(const short8*)(WcT + n * H + q * 32 + quad * 8);
      bhr[q][ct] = *(const short8*)(WrT + n * H + q * 32 + quad * 8);
    }
#pragma unroll
  for (int p = 0; p < 4; ++p) {
    int fi = t + p * 256;
    int row = fi >> 4, c8 = (fi & 15) * 8;
    int gn = n0 + row; if (gn >= N_NODES) gn = N_NODES - 1;
    *(uint4*)(sA + row * 136 + c8) = *(const uint4*)(A + (size_t)gn * H + c8);
  }
  __syncthreads();
  f32x4 accC[2][2], accR[2][2];
#pragma unroll
  for (int i = 0; i < 2; ++i)
#pragma unroll
    for (int jj = 0; jj < 2; ++jj) {
      accC[i][jj] = (f32x4){0.f, 0.f, 0.f, 0.f};
      accR[i][jj] = (f32x4){0.f, 0.f, 0.f, 0.f};
    }
#pragma unroll
  for (int q = 0; q < 4; ++q) {
    short8 ah[2];
#pragma unroll
    for (int rt = 0; rt < 2; ++rt)
      ah[rt] = *(const short8*)(sA + (wr * 32 + rt * 16 + m) * 136 + q * 32 + quad * 8);
#pragma unroll
    for (int rt = 0; rt < 2; ++rt)
#pragma unroll
      for (int ct = 0; ct < 2; ++ct) {
        accC[rt][ct] = __builtin_amdgcn_mfma_f32_16x16x32_bf16(ah[rt], bhc[q][ct], accC[rt][ct], 0, 0, 0);
        accR[rt][ct] = __builtin_amdgcn_mfma_f32_16x16x32_bf16(ah[rt], bhr[q][ct], accR[rt][ct], 0, 0, 0);
      }
  }
#pragma unroll
  for (int rt = 0; rt < 2; ++rt)
#pragma unroll
    for (int ct = 0; ct < 2; ++ct) {
      int col = c0 + wc * 32 + ct * 16 + m;
      float bv = bias[col];
#pragma unroll
      for (int rr = 0; rr < 4; ++rr) {
        int gn = n0 + wr * 32 + rt * 16 + quad * 4 + rr;
        if (gn < N_NODES) {
          ht8[(size_t)gn * H + col]  = f32_to_fp8(accC[rt][ct][rr]);
          resb[(size_t)gn * H + col] = f2bf(accR[rt][ct][rr] + bv);
        }
      }
    }
}

// ---------------- aggregate(fp8 ht) + bias + LN + relu + residual(bf16) ----------------
// r14 layout (4 groups x 16 lanes, uint2 gathers), 32-edge rounds + 16-slot
// tail. r17: (a) 512-thr blocks / 8 nodes — occupancy was pinned at 16
// waves/CU (4 wg/CU limit, 44 VGPR can't explain it); (b) fv2 accumulators
// so fma pairs contract to v_pk_fma_f32; (c) 32-bit voffset addressing
// (uniform ht8 base -> saddr form, 1 VALU/gather instead of 64-bit chain).
template <int NJ>
__device__ __forceinline__ void agg_round(const unsigned char* __restrict__ ht8,
                                          unsigned flo, int e0, int grp,
                                          int s, float w, fv2* acc2) {
  uint2 uu[NJ]; float ww[NJ];
#pragma unroll
  for (int jj = 0; jj < NJ; ++jj) {
    int idx = e0 + jj * 4 + grp;   // < 64 always
    int ss = __shfl(s, idx, 64);
    ww[jj] = __shfl(w, idx, 64);
    uu[jj] = *(const uint2*)(ht8 + (((unsigned)ss << 7) | flo));
  }
#pragma unroll
  for (int jj = 0; jj < NJ; ++jj) {
    float we = ww[jj];
    fv2 we2 = {we, we};
    fv2 a = fp8x2<false>(uu[jj].x), b = fp8x2<true>(uu[jj].x);
    fv2 c = fp8x2<false>(uu[jj].y), d2 = fp8x2<true>(uu[jj].y);
    acc2[0] += we2 * a;
    acc2[1] += we2 * b;
    acc2[2] += we2 * c;
    acc2[3] += we2 * d2;
  }
}

__global__ __launch_bounds__(512) void k_agg(
    const unsigned char* __restrict__ ht8, const unsigned short* __restrict__ res,
    const float* __restrict__ dinv, const int* __restrict__ offs,
    const int* __restrict__ parts, const int* __restrict__ degT,
    const unsigned* __restrict__ csr,
    const float* __restrict__ bias, const float* __restrict__ lng,
    const float* __restrict__ lnb, unsigned short* __restrict__ hout) {
  int wid = threadIdx.x >> 6, lane = threadIdx.x & 63;
  int node = blockIdx.x * 8 + wid;
  if (node >= N_NODES) return;
  int grp = lane >> 4, fl = lane & 15;
  unsigned flo = (unsigned)fl * 8u;
  int start = offs[node] + parts[node >> 8], cnt = degT[node];
  float di = dinv[node];
  fv2 acc2[4];
  {
    uint2 u = *(const uint2*)(ht8 + (((unsigned)node << 7) | flo));
    float sw = (grp == 0) ? di * di : 0.f;
    fv2 sw2 = {sw, sw};
    acc2[0] = sw2 * fp8x2<false>(u.x);
    acc2[1] = sw2 * fp8x2<true>(u.x);
    acc2[2] = sw2 * fp8x2<false>(u.y);
    acc2[3] = sw2 * fp8x2<true>(u.y);
  }
  float ddq = di * (1.f / 32767.f);
  for (int b0 = 0; b0 < cnt; b0 += 64) {
    int mm_ = min(64, cnt - b0);
    int s = 0; float w = 0.f;
    if (lane < mm_) {
      unsigned ev = csr[start + b0 + lane];
      s = (int)(ev >> 15);
      w = (float)(ev & 32767u) * ddq;
    }
    int e0 = 0;
    for (; e0 + 32 <= mm_; e0 += 32) agg_round<8>(ht8, flo, e0, grp, s, w, acc2);
    int rem = mm_ - e0;
    if (rem > 16)      agg_round<8>(ht8, flo, e0, grp, s, w, acc2);
    else if (rem > 0)  agg_round<4>(ht8, flo, e0, grp, s, w, acc2);
  }
  float acc[8] = {acc2[0].x, acc2[0].y, acc2[1].x, acc2[1].y,
                  acc2[2].x, acc2[2].y, acc2[3].x, acc2[3].y};
#pragma unroll
  for (int j = 0; j < 8; ++j) {
    acc[j] += __shfl_xor(acc[j], 16, 64);
    acc[j] += __shfl_xor(acc[j], 32, 64);
  }
  float4 b0v = *(const float4*)(bias + fl * 8);
  float4 b1v = *(const float4*)(bias + fl * 8 + 4);
  acc[0] += b0v.x; acc[1] += b0v.y; acc[2] += b0v.z; acc[3] += b0v.w;
  acc[4] += b1v.x; acc[5] += b1v.y; acc[6] += b1v.z; acc[7] += b1v.w;
  float sl = ((acc[0] + acc[1]) + (acc[2] + acc[3])) +
             ((acc[4] + acc[5]) + (acc[6] + acc[7]));
#pragma unroll
  for (int mk = 1; mk <= 8; mk <<= 1) sl += __shfl_xor(sl, mk, 64);
  float mu = sl * (1.f / 128.f);
  float d[8];
  float vl = 0.f;
#pragma unroll
  for (int j = 0; j < 8; ++j) { d[j] = acc[j] - mu; vl = fmaf(d[j], d[j], vl); }
#pragma unroll
  for (int mk = 1; mk <= 8; mk <<= 1) vl += __shfl_xor(vl, mk, 64);
  float rs = rsqrtf(vl * (1.f / 128.f) + EPS);
  if (grp == 0) {
    float4 g0 = *(const float4*)(lng + fl * 8);
    float4 g1 = *(const float4*)(lng + fl * 8 + 4);
    float4 be0 = *(const float4*)(lnb + fl * 8);
    float4 be1 = *(const float4*)(lnb + fl * 8 + 4);
    uint4 rv = *(const uint4*)(res + (size_t)node * 128 + fl * 8);
    float o0 = fmaxf(fmaf(d[0] * rs, g0.x, be0.x), 0.f) + bflo(rv.x);
    float o1 = fmaxf(fmaf(d[1] * rs, g0.y, be0.y), 0.f) + bfhi(rv.x);
    float o2 = fmaxf(fmaf(d[2] * rs, g0.z, be0.z), 0.f) + bflo(rv.y);
    float o3 = fmaxf(fmaf(d[3] * rs, g0.w, be0.w), 0.f) + bfhi(rv.y);
    float o4 = fmaxf(fmaf(d[4] * rs, g1.x, be1.x), 0.f) + bflo(rv.z);
    float o5 = fmaxf(fmaf(d[5] * rs, g1.y, be1.y), 0.f) + bfhi(rv.z);
    float o6 = fmaxf(fmaf(d[6] * rs, g1.z, be1.z), 0.f) + bflo(rv.w);
    float o7 = fmaxf(fmaf(d[7] * rs, g1.w, be1.w), 0.f) + bfhi(rv.w);
    uint4 ov;
    ov.x = pack2(o0, o1); ov.y = pack2(o2, o3);
    ov.z = pack2(o4, o5); ov.w = pack2(o6, o7);
    *(uint4*)(hout + (size_t)node * 128 + fl * 8) = ov;
  }
}

// ---------------- mean pool (bf16 h, vectorized uint4 loads) ----------------
__global__ __launch_bounds__(256) void k_pool(const unsigned short* __restrict__ h,
                                              float* __restrict__ pool) {
  __shared__ float colsum[128];
  int t = threadIdx.x;
  if (t < 128) colsum[t] = 0.f;
  __syncthreads();
  int lr = t >> 4, seg = t & 15;   // 16 rows/pass, 16 x uint4 per row
  float acc[8] = {0.f, 0.f, 0.f, 0.f, 0.f, 0.f, 0.f, 0.f};
  for (int n = blockIdx.x * 16 + lr; n < N_NODES; n += gridDim.x * 16) {
    uint4 u = *(const uint4*)(h + (size_t)n * H + seg * 8);
    acc[0] += bflo(u.x); acc[1] += bfhi(u.x);
    acc[2] += bflo(u.y); acc[3] += bfhi(u.y);
    acc[4] += bflo(u.z); acc[5] += bfhi(u.z);
    acc[6] += bflo(u.w); acc[7] += bfhi(u.w);
  }
#pragma unroll
  for (int j = 0; j < 8; ++j) atomicAdd(&colsum[seg * 8 + j], acc[j]);
  __syncthreads();
  if (t < 128) atomicAdd(&pool[t], colsum[t]);
}

// ---------------- head ----------------
__global__ void k_head(const float* __restrict__ pool, const float* __restrict__ Wfc1,
                       const float* __restrict__ bfc1, const float* __restrict__ g,
                       const float* __restrict__ bb, const float* __restrict__ Wfc2,
                       const float* __restrict__ bfc2, float* __restrict__ out) {
  __shared__ float sm[128], s1[128], stats[2];
  int t = threadIdx.x;
  if (t < 128) sm[t] = pool[t] * (1.f / (float)N_NODES);
  __syncthreads();
  if (t < 128) {
    float a = bfc1[t];
    for (int k = 0; k < 128; ++k) a = fmaf(sm[k], Wfc1[k * 128 + t], a);
    s1[t] = a;
  }
  __syncthreads();
  if (t == 0) {
    float mu = 0.f;
    for (int k = 0; k < 128; ++k) mu += s1[k];
    mu *= (1.f / 128.f);
    float var = 0.f;
    for (int k = 0; k < 128; ++k) { float d = s1[k] - mu; var += d * d; }
    var *= (1.f / 128.f);
    stats[0] = mu; stats[1] = rsqrtf(var + EPS);
  }
  __syncthreads();
  if (t < 128) s1[t] = fmaxf((s1[t] - stats[0]) * stats[1] * g[t] + bb[t], 0.f);
  __syncthreads();
  if (t < OUT_F) {
    float a = bfc2[t];
    for (int k = 0; k < 128; ++k) a = fmaf(s1[k], Wfc2[k * OUT_F + t], a);
    out[t] = a;
  }
}

extern "C" void kernel_launch(void* const* d_in, const int* in_sizes, int n_in,
                              void* d_out, int out_size, void* d_ws, size_t ws_size,
                              hipStream_t stream) {
  const float* x      = (const float*)d_in[0];
  const int*   ei     = (const int*)d_in[1];
  const float* W_emb  = (const float*)d_in[2];
  const float* b_emb  = (const float*)d_in[3];
  const float* W_conv = (const float*)d_in[4];
  const float* b_conv = (const float*)d_in[5];
  const float* ln_g   = (const float*)d_in[6];
  const float* ln_b   = (const float*)d_in[7];
  const float* W_res  = (const float*)d_in[8];
  const float* b_res  = (const float*)d_in[9];
  const float* W_fc1  = (const float*)d_in[10];
  const float* b_fc1  = (const float*)d_in[11];
  const float* fcn_g  = (const float*)d_in[12];
  const float* fcn_b  = (const float*)d_in[13];
  const float* W_fc2  = (const float*)d_in[14];
  const float* b_fc2  = (const float*)d_in[15];
  float* out = (float*)d_out;

  char* p = (char*)d_ws;
  auto take = [&](size_t bytes) {
    char* r = p; p += (bytes + 255) & ~(size_t)255; return r;
  };
  unsigned short* bufA = (unsigned short*)take((size_t)N_NODES * H * 2);
  unsigned short* bufB = (unsigned short*)take((size_t)N_NODES * H * 2);
  unsigned short* bufC = (unsigned short*)take((size_t)N_NODES * H * 2);
  unsigned char*  ht8  = (unsigned char*)take((size_t)N_NODES * H);
  unsigned short* whiT = (unsigned short*)take((size_t)5 * H * H * 2);
  int*   deg8 = (int*)take((size_t)NXCD * N_NODES * 4);
  int*   degT = (int*)take(N_NODES * 4);
  int*   offs = (int*)take(N_NODES * 4);
  uint2* xp8  = (uint2*)take((size_t)N_NODES * 8);
  int*   parts= (int*)take(512 * 4);
  float* dinv = (float*)take(N_NODES * 4);
  unsigned short* ranks16 = (unsigned short*)take((size_t)NEDGES * 2);
  unsigned* csr = (unsigned*)take((size_t)NEDGES * 4);
  float* pool = (float*)take(128 * 4);

  (void)hipMemsetAsync(deg8, 0, (size_t)NXCD * N_NODES * 4, stream);
  (void)hipMemsetAsync(pool, 0, 128 * 4, stream);

  k_ws<<<WS_BLKS, 256, 0, stream>>>(W_conv, W_res, whiT);
  k_pre3<<<PRE3_BLKS, 256, 0, stream>>>(ei, deg8, ranks16, x, W_emb, b_emb, bufA,
                                        whiT + 0 * H * H, ht8);
  k_scan_a<<<NPARTS, 256, 0, stream>>>(deg8, degT, offs, xp8, parts, dinv);
  k_scan_b<<<1, 512, 0, stream>>>(parts, NPARTS);
  k_fill<<<FILL_BLKS, 256, 0, stream>>>(ei, ranks16, offs, xp8, parts, dinv, csr);

  // L0: res=h0=A -> h1=C
  k_agg<<<AGG_BLKS, 512, 0, stream>>>(ht8, bufA, dinv, offs, parts, degT, csr,
                                      b_conv + 0 * H, ln_g + 0 * H, ln_b + 0 * H, bufC);
  // L1: h1=C -> ht8 -> h2=A (res=C)
  k_mm<<<MM_BLKS, 256, 0, stream>>>(bufC, whiT + 1 * H * H, ht8);
  k_agg<<<AGG_BLKS, 512, 0, stream>>>(ht8, bufC, dinv, offs, parts, degT, csr,
                                      b_conv + 1 * H, ln_g + 1 * H, ln_b + 1 * H, bufA);
  // L2: h2=A; dual: ht8=A@W2, B=bf16(A@Wres+bres); agg -> h3=C (res=B)
  k_mmd<<<MM_BLKS, 256, 0, stream>>>(bufA, whiT + 2 * H * H, whiT + 4 * H * H,
                                     b_res, ht8, bufB);
  k_agg<<<AGG_BLKS, 512, 0, stream>>>(ht8, bufB, dinv, offs, parts, degT, csr,
                                      b_conv + 2 * H, ln_g + 2 * H, ln_b + 2 * H, bufC);
  // L3: h3=C -> ht8 -> h4=A (res=C)
  k_mm<<<MM_BLKS, 256, 0, stream>>>(bufC, whiT + 3 * H * H, ht8);
  k_agg<<<AGG_BLKS, 512, 0, stream>>>(ht8, bufC, dinv, offs, parts, degT, csr,
                                      b_conv + 3 * H, ln_g + 3 * H, ln_b + 3 * H, bufA);

  k_pool<<<256, 256, 0, stream>>>(bufA, pool);
  k_head<<<1, 256, 0, stream>>>(pool, W_fc1, b_fc1, fcn_g, fcn_b,
                                W_fc2, b_fc2, out);
}

// Round 3
// 487.816 us; speedup vs baseline: 1.2203x; 1.1455x over previous
//
#include <hip/hip_runtime.h>

constexpr int N_NODES = 100000;
constexpr int F_IN    = 32;
constexpr int H       = 128;
constexpr int OUT_F   = 200;
constexpr int NEDGES  = 1600000;
constexpr float EPS   = 1e-5f;
constexpr int NXCD    = 8;

constexpr int HIST8_BLKS = (NEDGES / 8 + 255) / 256;  // 782
constexpr int WS_BLKS    = 80;                        // 5*128*128/1024
constexpr int NPARTS     = (N_NODES + 255) / 256;     // 391
constexpr int FILL_BLKS  = (NEDGES / 4 + 255) / 256;  // 1563
constexpr int TILE_BLKS  = (N_NODES + 63) / 64;       // 1563
constexpr int PRE3_BLKS  = HIST8_BLKS + TILE_BLKS;    // 2345 (1:2 interleave)
constexpr int MM_BLKS    = TILE_BLKS * 2;             // 3126 (64r x 64c tiles)
constexpr int AGG_BLKS   = N_NODES / 32;              // 3125 (512 thr, 32 nodes, exact)

typedef __attribute__((ext_vector_type(8))) short  short8;
typedef __attribute__((ext_vector_type(4))) float  f32x4;
typedef __attribute__((ext_vector_type(2))) float  fv2;

__device__ __forceinline__ void fma4(float4& a, float s, const float4& w) {
  a.x = fmaf(s, w.x, a.x); a.y = fmaf(s, w.y, a.y);
  a.z = fmaf(s, w.z, a.z); a.w = fmaf(s, w.w, a.w);
}

__device__ __forceinline__ unsigned short f2bf(float f) {  // RNE
  union { float f; unsigned u; } v; v.f = f;
  unsigned r = v.u + 0x7fffu + ((v.u >> 16) & 1u);
  return (unsigned short)(r >> 16);
}
__device__ __forceinline__ float bf2f(unsigned short s) {
  union { unsigned u; float f; } v; v.u = ((unsigned)s) << 16;
  return v.f;
}
__device__ __forceinline__ float bflo(unsigned u) { return __uint_as_float(u << 16); }
__device__ __forceinline__ float bfhi(unsigned u) { return __uint_as_float(u & 0xffff0000u); }
__device__ __forceinline__ unsigned pack2(float lo, float hi) {
  return (unsigned)f2bf(lo) | ((unsigned)f2bf(hi) << 16);
}
__device__ __forceinline__ void st_bf4(unsigned short* p, float4 v) {
  uint2 o; o.x = pack2(v.x, v.y); o.y = pack2(v.z, v.w);
  *(uint2*)p = o;
}

// ---------------- fp8 e4m3fn helpers ----------------
#if __has_builtin(__builtin_amdgcn_cvt_pk_f32_fp8) && __has_builtin(__builtin_amdgcn_cvt_pk_fp8_f32)
#define HAVE_FP8_CVT 1
#endif

#ifndef HAVE_FP8_CVT
__device__ __forceinline__ float fp8_dec1(unsigned b) {
  unsigned s = (b >> 7) & 1u, E = (b >> 3) & 15u, m = b & 7u;
  float v;
  if (E) {
    union { unsigned u; float f; } t;
    t.u = (s << 31) | ((E + 120u) << 23) | (m << 20);
    v = t.f;
  } else {
    v = (s ? -1.f : 1.f) * (float)m * 0.001953125f;
  }
  return v;
}
#endif

template <bool HI>
__device__ __forceinline__ fv2 fp8x2(unsigned u) {
#ifdef HAVE_FP8_CVT
  return __builtin_amdgcn_cvt_pk_f32_fp8((int)u, HI);
#else
  unsigned p = HI ? (u >> 16) : u;
  fv2 r; r.x = fp8_dec1(p & 0xffu); r.y = fp8_dec1((p >> 8) & 0xffu);
  return r;
#endif
}

__device__ __forceinline__ unsigned char f32_to_fp8(float f) {
#ifdef HAVE_FP8_CVT
  return (unsigned char)(__builtin_amdgcn_cvt_pk_fp8_f32(f, f, 0, false) & 0xff);
#else
  union { float f; unsigned u; } t; t.f = f;
  unsigned s = t.u >> 31;
  float a = fabsf(f);
  if (a > 448.f) a = 448.f;
  t.f = a;
  int e = (int)((t.u >> 23) & 0xff) - 127;
  unsigned char r;
  if (a == 0.f) {
    r = 0;
  } else if (e >= -6) {
    unsigned m = t.u & 0x7fffffu;
    unsigned keep = m >> 20, rest = m & 0xfffffu;
    keep += (rest > 0x80000u) || (rest == 0x80000u && (keep & 1u));
    int E = e + 7;
    if (keep == 8u) { keep = 0u; E += 1; }
    if (E >= 16) { E = 15; keep = 6u; }
    r = (unsigned char)((E << 3) | keep);
  } else {
    int mi = (int)(a * 512.f + 0.5f);
    r = (mi > 7) ? (unsigned char)(1u << 3) : (unsigned char)mi;
  }
  return (unsigned char)(r | (s << 7));
#endif
}

// ---------------- k_ws: W -> bf16 transposed ----------------
__global__ void k_ws(const float* __restrict__ W_conv,
                     const float* __restrict__ W_res,
                     unsigned short* __restrict__ whiT) {
  int base = blockIdx.x * 1024;
#pragma unroll
  for (int j = 0; j < 4; ++j) {
    int idx = base + j * 256 + threadIdx.x;
    if (idx < 5 * H * H) {
      int m = idx >> 14, rr = idx & 16383;
      int k = rr >> 7, n = rr & 127;
      const float* src = (m < 4) ? (W_conv + m * H * H) : W_res;
      whiT[m * H * H + n * H + k] = f2bf(src[k * H + n]);
    }
  }
}

// mm from LDS tile: 64 rows x 128 cols, wave = 32r x 64c (B frags hoisted)
__device__ __forceinline__ void mm_lds_fp8(const unsigned short* sA,
                                           const unsigned short* __restrict__ WT,
                                           int n0, int t,
                                           unsigned char* __restrict__ htOut) {
  int wave = t >> 6, lane = t & 63;
  int wr = wave >> 1, wc = wave & 1;
  int m = lane & 15, quad = (lane >> 4) & 3;
  short8 bh[4][4];
#pragma unroll
  for (int q = 0; q < 4; ++q)
#pragma unroll
    for (int ct = 0; ct < 4; ++ct) {
      int n = wc * 64 + ct * 16 + m;
      bh[q][ct] = *(const short8*)(WT + n * H + q * 32 + quad * 8);
    }
  f32x4 acc[2][4];
#pragma unroll
  for (int i = 0; i < 2; ++i)
#pragma unroll
    for (int j = 0; j < 4; ++j) acc[i][j] = (f32x4){0.f, 0.f, 0.f, 0.f};
#pragma unroll
  for (int q = 0; q < 4; ++q) {
    short8 ah[2];
#pragma unroll
    for (int rt = 0; rt < 2; ++rt)
      ah[rt] = *(const short8*)(sA + (wr * 32 + rt * 16 + m) * 136 + q * 32 + quad * 8);
#pragma unroll
    for (int rt = 0; rt < 2; ++rt)
#pragma unroll
      for (int ct = 0; ct < 4; ++ct)
        acc[rt][ct] = __builtin_amdgcn_mfma_f32_16x16x32_bf16(ah[rt], bh[q][ct], acc[rt][ct], 0, 0, 0);
  }
#pragma unroll
  for (int rt = 0; rt < 2; ++rt)
#pragma unroll
    for (int ct = 0; ct < 4; ++ct) {
      int col = wc * 64 + ct * 16 + m;
#pragma unroll
      for (int rr = 0; rr < 4; ++rr) {
        int gn = n0 + wr * 32 + rt * 16 + quad * 4 + rr;
        if (gn < N_NODES) htOut[(size_t)gn * H + col] = f32_to_fp8(acc[rt][ct][rr]);
      }
    }
}

// ---------------- k_pre3: hist | (embed 64-node tile -> LDS -> mm W0), 1:2 ----------------
// r16/r18 note: per-XCD workgroup-scope atomics did NOT change the atomic
// rate (8.3 -> 8.8/cycle) — global atomic RMWs appear to serialize at a
// shared point (~8.6/cycle device-wide) regardless of scope/slicing.
// Beating this requires fewer global atomics (LDS-bucketed sort) — deferred.
__global__ __launch_bounds__(256) void k_pre3(
    const int* __restrict__ ei, int* __restrict__ deg8,
    unsigned short* __restrict__ ranks16,
    const float* __restrict__ x, const float* __restrict__ W_emb,
    const float* __restrict__ b_emb, unsigned short* __restrict__ h,
    const unsigned short* __restrict__ W0T, unsigned char* __restrict__ ht8) {
  __shared__ __align__(16) char smem[25600];
  int t = threadIdx.x;
  int id = blockIdx.x;
  int q3 = id / 3, r3 = id - q3 * 3;
  if (r3 == 0) {
    unsigned xcd;
    asm("s_getreg_b32 %0, hwreg(HW_REG_XCC_ID)" : "=s"(xcd));
    xcd &= 7u;
    int* dslice = deg8 + (size_t)xcd * N_NODES;
    unsigned hx = xcd << 8;
    int i = q3 * 256 + t;
    if (i < NEDGES / 8) {
      int4 a = *(const int4*)(ei + NEDGES + 8 * i);
      int4 b = *(const int4*)(ei + NEDGES + 8 * i + 4);
      union { unsigned short u16[8]; uint4 u4; } rr;
      rr.u16[0] = (unsigned short)(hx | (unsigned)__hip_atomic_fetch_add(dslice + a.x, 1, __ATOMIC_RELAXED, __HIP_MEMORY_SCOPE_WORKGROUP));
      rr.u16[1] = (unsigned short)(hx | (unsigned)__hip_atomic_fetch_add(dslice + a.y, 1, __ATOMIC_RELAXED, __HIP_MEMORY_SCOPE_WORKGROUP));
      rr.u16[2] = (unsigned short)(hx | (unsigned)__hip_atomic_fetch_add(dslice + a.z, 1, __ATOMIC_RELAXED, __HIP_MEMORY_SCOPE_WORKGROUP));
      rr.u16[3] = (unsigned short)(hx | (unsigned)__hip_atomic_fetch_add(dslice + a.w, 1, __ATOMIC_RELAXED, __HIP_MEMORY_SCOPE_WORKGROUP));
      rr.u16[4] = (unsigned short)(hx | (unsigned)__hip_atomic_fetch_add(dslice + b.x, 1, __ATOMIC_RELAXED, __HIP_MEMORY_SCOPE_WORKGROUP));
      rr.u16[5] = (unsigned short)(hx | (unsigned)__hip_atomic_fetch_add(dslice + b.y, 1, __ATOMIC_RELAXED, __HIP_MEMORY_SCOPE_WORKGROUP));
      rr.u16[6] = (unsigned short)(hx | (unsigned)__hip_atomic_fetch_add(dslice + b.z, 1, __ATOMIC_RELAXED, __HIP_MEMORY_SCOPE_WORKGROUP));
      rr.u16[7] = (unsigned short)(hx | (unsigned)__hip_atomic_fetch_add(dslice + b.w, 1, __ATOMIC_RELAXED, __HIP_MEMORY_SCOPE_WORKGROUP));
      ((uint4*)ranks16)[i] = rr.u4;
    }
  } else {
    int j = q3 * 2 + (r3 - 1);
    int n0 = j * 64;
    float* sW = (float*)smem;
    float* sX = sW + 4096;
    unsigned short* sH = (unsigned short*)smem;
#pragma unroll
    for (int p = 0; p < 4; ++p)
      ((float4*)sW)[t + p * 256] = ((const float4*)W_emb)[t + p * 256];
#pragma unroll
    for (int p = 0; p < 2; ++p) {
      int fi = t * 2 + p;
      int row = fi >> 3, k4 = (fi & 7) * 4;
      int gn = n0 + row; if (gn >= N_NODES) gn = N_NODES - 1;
      *(float4*)(sX + row * 36 + k4) = *(const float4*)(x + (size_t)gn * F_IN + k4);
    }
    __syncthreads();
    // conflict-free sW reads: col0 = (t&3)*4 -> banks {0,4,8,12}(+16i)
    int nr = t >> 2, col0 = (t & 3) * 4;
    float4 acc[8];
#pragma unroll
    for (int i = 0; i < 8; ++i) acc[i] = make_float4(0.f, 0.f, 0.f, 0.f);
#pragma unroll 4
    for (int k = 0; k < F_IN; ++k) {
      float xv = sX[nr * 36 + k];
      const float* wp = sW + k * H + col0;
#pragma unroll
      for (int i = 0; i < 8; ++i) fma4(acc[i], xv, *(const float4*)(wp + i * 16));
    }
#pragma unroll
    for (int i = 0; i < 8; ++i) {
      float4 bv = *(const float4*)(b_emb + col0 + i * 16);
      acc[i].x += bv.x; acc[i].y += bv.y; acc[i].z += bv.z; acc[i].w += bv.w;
    }
    __syncthreads();  // done reading sW/sX; reuse as sH
    int node = n0 + nr;
    unsigned short* hr = h + (size_t)node * H + col0;
#pragma unroll
    for (int i = 0; i < 8; ++i) {
      st_bf4(sH + nr * 136 + col0 + i * 16, acc[i]);
      if (node < N_NODES) st_bf4(hr + i * 16, acc[i]);
    }
    __syncthreads();
    mm_lds_fp8(sH, W0T, n0, t, ht8);
  }
}

// ---------------- scans ----------------
// r17: fold 8 per-XCD slices into total degree + PACKED per-node slice
// prefixes (xp8: 8 bytes/node, valid since total deg < 256).
__global__ void k_scan_a(const int* __restrict__ deg8, int* __restrict__ degT,
                         int* __restrict__ offs, uint2* __restrict__ xp8,
                         int* __restrict__ parts, float* __restrict__ dinv) {
  __shared__ int s[256];
  int i = blockIdx.x * 256 + threadIdx.x;
  int d[NXCD];
  int tot = 0;
#pragma unroll
  for (int c = 0; c < NXCD; ++c) {
    d[c] = (i < N_NODES) ? deg8[(size_t)c * N_NODES + i] : 0;
    tot += d[c];
  }
  s[threadIdx.x] = tot;
  __syncthreads();
#pragma unroll
  for (int off = 1; off < 256; off <<= 1) {
    int v = (threadIdx.x >= off) ? s[threadIdx.x - off] : 0;
    __syncthreads();
    s[threadIdx.x] += v;
    __syncthreads();
  }
  if (i < N_NODES) {
    offs[i] = s[threadIdx.x] - tot;   // block-local exclusive
    degT[i] = tot;
    dinv[i] = rsqrtf((float)(tot + 1));
    unsigned p = 0, lo = 0, hi = 0;
#pragma unroll
    for (int c = 0; c < 4; ++c) { lo |= (p & 255u) << (8 * c); p += (unsigned)d[c]; }
#pragma unroll
    for (int c = 4; c < 8; ++c) { hi |= (p & 255u) << (8 * (c - 4)); p += (unsigned)d[c]; }
    uint2 xp; xp.x = lo; xp.y = hi;
    xp8[i] = xp;
  }
  if (threadIdx.x == 255) parts[blockIdx.x] = s[255];
}

__global__ void k_scan_b(int* __restrict__ parts, int nparts) {
  __shared__ int s[512];
  int t = threadIdx.x;
  int d = (t < nparts) ? parts[t] : 0;
  s[t] = d;
  __syncthreads();
#pragma unroll
  for (int off = 1; off < 512; off <<= 1) {
    int v = (t >= off) ? s[t - off] : 0;
    __syncthreads();
    s[t] += v;
    __syncthreads();
  }
  if (t < nparts) parts[t] = s[t] - d;
}

// ---------------- k_fill ----------------
__global__ __launch_bounds__(256) void k_fill(
    const int* __restrict__ ei, const unsigned short* __restrict__ ranks16,
    const int* __restrict__ offs, const uint2* __restrict__ xp8,
    const int* __restrict__ parts,
    const float* __restrict__ dinv, unsigned* __restrict__ csr) {
  int i = blockIdx.x * 256 + threadIdx.x;
  if (i < NEDGES / 4) {
    int4 s4 = *(const int4*)(ei + 4 * i);
    int4 d4 = *(const int4*)(ei + NEDGES + 4 * i);
    uint2 rv = ((const uint2*)ranks16)[i];
    unsigned r0 = rv.x & 0xffffu, r1 = rv.x >> 16;
    unsigned r2 = rv.y & 0xffffu, r3 = rv.y >> 16;
    auto pos = [&](int dst, unsigned r) {
      uint2 xp = xp8[dst];
      unsigned xc = r >> 8;
      unsigned pre = ((xc < 4u) ? (xp.x >> (xc * 8u)) : (xp.y >> ((xc - 4u) * 8u))) & 255u;
      return offs[dst] + parts[dst >> 8] + (int)pre + (int)(r & 255u);
    };
    int p0 = pos(d4.x, r0);
    int p1 = pos(d4.y, r1);
    int p2 = pos(d4.z, r2);
    int p3 = pos(d4.w, r3);
    csr[p0] = ((unsigned)s4.x << 15) | (unsigned)(dinv[s4.x] * 32767.f + 0.5f);
    csr[p1] = ((unsigned)s4.y << 15) | (unsigned)(dinv[s4.y] * 32767.f + 0.5f);
    csr[p2] = ((unsigned)s4.z << 15) | (unsigned)(dinv[s4.z] * 32767.f + 0.5f);
    csr[p3] = ((unsigned)s4.w << 15) | (unsigned)(dinv[s4.w] * 32767.f + 0.5f);
  }
}

// ---------------- mm core for layers 1-3 (global A) ----------------
struct MMAcc { f32x4 a[2][2]; };

__device__ __forceinline__ MMAcc mm_core(const unsigned short* __restrict__ A,
                                         const unsigned short* __restrict__ WhiT,
                                         int n0, int c0, int t,
                                         unsigned short* sA) {
  int wave = t >> 6, lane = t & 63;
  int wr = wave >> 1, wc = wave & 1;
  int m = lane & 15, quad = (lane >> 4) & 3;
  short8 bh[4][2];
#pragma unroll
  for (int q = 0; q < 4; ++q)
#pragma unroll
    for (int ct = 0; ct < 2; ++ct) {
      int n = c0 + wc * 32 + ct * 16 + m;
      bh[q][ct] = *(const short8*)(WhiT + n * H + q * 32 + quad * 8);
    }
#pragma unroll
  for (int p = 0; p < 4; ++p) {
    int fi = t + p * 256;
    int row = fi >> 4, c8 = (fi & 15) * 8;
    int gn = n0 + row; if (gn >= N_NODES) gn = N_NODES - 1;
    *(uint4*)(sA + row * 136 + c8) = *(const uint4*)(A + (size_t)gn * H + c8);
  }
  __syncthreads();
  MMAcc r;
#pragma unroll
  for (int i = 0; i < 2; ++i)
#pragma unroll
    for (int j = 0; j < 2; ++j) r.a[i][j] = (f32x4){0.f, 0.f, 0.f, 0.f};
#pragma unroll
  for (int q = 0; q < 4; ++q) {
    short8 ah[2];
#pragma unroll
    for (int rt = 0; rt < 2; ++rt)
      ah[rt] = *(const short8*)(sA + (wr * 32 + rt * 16 + m) * 136 + q * 32 + quad * 8);
#pragma unroll
    for (int rt = 0; rt < 2; ++rt)
#pragma unroll
      for (int ct = 0; ct < 2; ++ct)
        r.a[rt][ct] = __builtin_amdgcn_mfma_f32_16x16x32_bf16(ah[rt], bh[q][ct], r.a[rt][ct], 0, 0, 0);
  }
  return r;
}

__device__ __forceinline__ void mm_store_fp8(const MMAcc& r, unsigned char* ht8,
                                             int n0, int c0, int t) {
  int wave = t >> 6, lane = t & 63;
  int wr = wave >> 1, wc = wave & 1;
  int m = lane & 15, quad = (lane >> 4) & 3;
#pragma unroll
  for (int rt = 0; rt < 2; ++rt)
#pragma unroll
    for (int ct = 0; ct < 2; ++ct) {
      int col = c0 + wc * 32 + ct * 16 + m;
#pragma unroll
      for (int rr = 0; rr < 4; ++rr) {
        int gn = n0 + wr * 32 + rt * 16 + quad * 4 + rr;
        if (gn < N_NODES) ht8[(size_t)gn * H + col] = f32_to_fp8(r.a[rt][ct][rr]);
      }
    }
}

__global__ __launch_bounds__(256) void k_mm(const unsigned short* __restrict__ A,
                                            const unsigned short* __restrict__ WhiT,
                                            unsigned char* __restrict__ ht8) {
  __shared__ __align__(16) unsigned short sA[64 * 136];
  int j = blockIdx.x;
  int n0 = (j >> 1) * 64, c0 = (j & 1) * 64;
  MMAcc r = mm_core(A, WhiT, n0, c0, threadIdx.x, sA);
  mm_store_fp8(r, ht8, n0, c0, threadIdx.x);
}

// layer-2 dual GEMM
__global__ __launch_bounds__(256) void k_mmd(const unsigned short* __restrict__ A,
    const unsigned short* __restrict__ WcT, const unsigned short* __restrict__ WrT,
    const float* __restrict__ bias,
    unsigned char* __restrict__ ht8, unsigned short* __restrict__ resb) {
  __shared__ __align__(16) unsigned short sA[64 * 136];
  int t = threadIdx.x;
  int j = blockIdx.x;
  int n0 = (j >> 1) * 64, c0 = (j & 1) * 64;
  int wave = t >> 6, lane = t & 63;
  int wr = wave >> 1, wc = wave & 1;
  int m = lane & 15, quad = (lane >> 4) & 3;
  short8 bhc[4][2], bhr[4][2];
#pragma unroll
  for (int q = 0; q < 4; ++q)
#pragma unroll
    for (int ct = 0; ct < 2; ++ct) {
      int n = c0 + wc * 32 + ct * 16 + m;
      bhc[q][ct] = *(const short8*)(WcT + n * H + q * 32 + quad * 8);
      bhr[q][ct] = *(const short8*)(WrT + n * H + q * 32 + quad * 8);
    }
#pragma unroll
  for (int p = 0; p < 4; ++p) {
    int fi = t + p * 256;
    int row = fi >> 4, c8 = (fi & 15) * 8;
    int gn = n0 + row; if (gn >= N_NODES) gn = N_NODES - 1;
    *(uint4*)(sA + row * 136 + c8) = *(const uint4*)(A + (size_t)gn * H + c8);
  }
  __syncthreads();
  f32x4 accC[2][2], accR[2][2];
#pragma unroll
  for (int i = 0; i < 2; ++i)
#pragma unroll
    for (int jj = 0; jj < 2; ++jj) {
      accC[i][jj] = (f32x4){0.f, 0.f, 0.f, 0.f};
      accR[i][jj] = (f32x4){0.f, 0.f, 0.f, 0.f};
    }
#pragma unroll
  for (int q = 0; q < 4; ++q) {
    short8 ah[2];
#pragma unroll
    for (int rt = 0; rt < 2; ++rt)
      ah[rt] = *(const short8*)(sA + (wr * 32 + rt * 16 + m) * 136 + q * 32 + quad * 8);
#pragma unroll
    for (int rt = 0; rt < 2; ++rt)
#pragma unroll
      for (int ct = 0; ct < 2; ++ct) {
        accC[rt][ct] = __builtin_amdgcn_mfma_f32_16x16x32_bf16(ah[rt], bhc[q][ct], accC[rt][ct], 0, 0, 0);
        accR[rt][ct] = __builtin_amdgcn_mfma_f32_16x16x32_bf16(ah[rt], bhr[q][ct], accR[rt][ct], 0, 0, 0);
      }
  }
#pragma unroll
  for (int rt = 0; rt < 2; ++rt)
#pragma unroll
    for (int ct = 0; ct < 2; ++ct) {
      int col = c0 + wc * 32 + ct * 16 + m;
      float bv = bias[col];
#pragma unroll
      for (int rr = 0; rr < 4; ++rr) {
        int gn = n0 + wr * 32 + rt * 16 + quad * 4 + rr;
        if (gn < N_NODES) {
          ht8[(size_t)gn * H + col]  = f32_to_fp8(accC[rt][ct][rr]);
          resb[(size_t)gn * H + col] = f2bf(accR[rt][ct][rr] + bv);
        }
      }
    }
}

// ---------------- aggregate(fp8 ht) + bias + LN + relu + residual(bf16) ----------------
// r18: ONE NODE PER 16-LANE GROUP (4 nodes/wave). Diagnosis: r17's
// occupancy x2 + VALU diet bought only ~4us -> k_agg is LATENCY-bound on
// the serial per-node chain (BW floor ~12us, VALU floor ~3us, measured
// ~72us). The 16 lanes of a group already cover a full 128B row, so groups
// are independent: 4x node-level MLP, zero cross-group feature reduction
// (each lane owns features fl*8..fl*8+7 end-to-end), LN reduces via 4-step
// shfl_xor within 16 lanes, and all 64 lanes write output. Tail slots are
// predicated to (src=node, w=0): branch-free, gathers the L1-hot own row.
__device__ __forceinline__ void agg_round8(const unsigned char* __restrict__ ht8,
                                           unsigned flo, int gbase, int e0,
                                           int s, float w, fv2* acc2) {
  uint2 uu[8]; float ww[8];
#pragma unroll
  for (int jj = 0; jj < 8; ++jj) {
    int ss = __shfl(s, gbase + e0 + jj, 64);
    ww[jj] = __shfl(w, gbase + e0 + jj, 64);
    uu[jj] = *(const uint2*)(ht8 + (((unsigned)ss << 7) | flo));
  }
#pragma unroll
  for (int jj = 0; jj < 8; ++jj) {
    float we = ww[jj];
    fv2 we2 = {we, we};
    acc2[0] += we2 * fp8x2<false>(uu[jj].x);
    acc2[1] += we2 * fp8x2<true>(uu[jj].x);
    acc2[2] += we2 * fp8x2<false>(uu[jj].y);
    acc2[3] += we2 * fp8x2<true>(uu[jj].y);
  }
}

__global__ __launch_bounds__(512) void k_agg(
    const unsigned char* __restrict__ ht8, const unsigned short* __restrict__ res,
    const float* __restrict__ dinv, const int* __restrict__ offs,
    const int* __restrict__ parts, const int* __restrict__ degT,
    const unsigned* __restrict__ csr,
    const float* __restrict__ bias, const float* __restrict__ lng,
    const float* __restrict__ lnb, unsigned short* __restrict__ hout) {
  int t = threadIdx.x;
  int fl = t & 15;
  int gbase = t & 48;                    // group base lane within wave
  int node = blockIdx.x * 32 + (t >> 4); // exact: 3125*32 == 100000
  unsigned flo = (unsigned)fl * 8u;
  int start = offs[node] + parts[node >> 8], cnt = degT[node];
  float di = dinv[node];
  fv2 acc2[4];
  {
    uint2 u = *(const uint2*)(ht8 + (((unsigned)node << 7) | flo));
    float sw = di * di;
    fv2 sw2 = {sw, sw};
    acc2[0] = sw2 * fp8x2<false>(u.x);
    acc2[1] = sw2 * fp8x2<true>(u.x);
    acc2[2] = sw2 * fp8x2<false>(u.y);
    acc2[3] = sw2 * fp8x2<true>(u.y);
  }
  float ddq = di * (1.f / 32767.f);
  for (int b0 = 0; b0 < cnt; b0 += 16) {
    int m = min(16, cnt - b0);
    int s = node; float w = 0.f;
    if (fl < m) {
      unsigned ev = csr[start + b0 + fl];
      s = (int)(ev >> 15);
      w = (float)(ev & 32767u) * ddq;
    }
    agg_round8(ht8, flo, gbase, 0, s, w, acc2);
    if (m > 8) agg_round8(ht8, flo, gbase, 8, s, w, acc2);
  }
  float acc[8] = {acc2[0].x, acc2[0].y, acc2[1].x, acc2[1].y,
                  acc2[2].x, acc2[2].y, acc2[3].x, acc2[3].y};
  float4 b0v = *(const float4*)(bias + fl * 8);
  float4 b1v = *(const float4*)(bias + fl * 8 + 4);
  acc[0] += b0v.x; acc[1] += b0v.y; acc[2] += b0v.z; acc[3] += b0v.w;
  acc[4] += b1v.x; acc[5] += b1v.y; acc[6] += b1v.z; acc[7] += b1v.w;
  float sl = ((acc[0] + acc[1]) + (acc[2] + acc[3])) +
             ((acc[4] + acc[5]) + (acc[6] + acc[7]));
#pragma unroll
  for (int mk = 1; mk <= 8; mk <<= 1) sl += __shfl_xor(sl, mk, 16);
  float mu = sl * (1.f / 128.f);
  float d[8];
  float vl = 0.f;
#pragma unroll
  for (int j = 0; j < 8; ++j) { d[j] = acc[j] - mu; vl = fmaf(d[j], d[j], vl); }
#pragma unroll
  for (int mk = 1; mk <= 8; mk <<= 1) vl += __shfl_xor(vl, mk, 16);
  float rs = rsqrtf(vl * (1.f / 128.f) + EPS);
  float4 g0 = *(const float4*)(lng + fl * 8);
  float4 g1 = *(const float4*)(lng + fl * 8 + 4);
  float4 be0 = *(const float4*)(lnb + fl * 8);
  float4 be1 = *(const float4*)(lnb + fl * 8 + 4);
  uint4 rv = *(const uint4*)(res + (size_t)node * 128 + fl * 8);
  float o0 = fmaxf(fmaf(d[0] * rs, g0.x, be0.x), 0.f) + bflo(rv.x);
  float o1 = fmaxf(fmaf(d[1] * rs, g0.y, be0.y), 0.f) + bfhi(rv.x);
  float o2 = fmaxf(fmaf(d[2] * rs, g0.z, be0.z), 0.f) + bflo(rv.y);
  float o3 = fmaxf(fmaf(d[3] * rs, g0.w, be0.w), 0.f) + bfhi(rv.y);
  float o4 = fmaxf(fmaf(d[4] * rs, g1.x, be1.x), 0.f) + bflo(rv.z);
  float o5 = fmaxf(fmaf(d[5] * rs, g1.y, be1.y), 0.f) + bfhi(rv.z);
  float o6 = fmaxf(fmaf(d[6] * rs, g1.z, be1.z), 0.f) + bflo(rv.w);
  float o7 = fmaxf(fmaf(d[7] * rs, g1.w, be1.w), 0.f) + bfhi(rv.w);
  uint4 ov;
  ov.x = pack2(o0, o1); ov.y = pack2(o2, o3);
  ov.z = pack2(o4, o5); ov.w = pack2(o6, o7);
  *(uint4*)(hout + (size_t)node * 128 + fl * 8) = ov;
}

// ---------------- mean pool (bf16 h, vectorized uint4 loads) ----------------
__global__ __launch_bounds__(256) void k_pool(const unsigned short* __restrict__ h,
                                              float* __restrict__ pool) {
  __shared__ float colsum[128];
  int t = threadIdx.x;
  if (t < 128) colsum[t] = 0.f;
  __syncthreads();
  int lr = t >> 4, seg = t & 15;   // 16 rows/pass, 16 x uint4 per row
  float acc[8] = {0.f, 0.f, 0.f, 0.f, 0.f, 0.f, 0.f, 0.f};
  for (int n = blockIdx.x * 16 + lr; n < N_NODES; n += gridDim.x * 16) {
    uint4 u = *(const uint4*)(h + (size_t)n * H + seg * 8);
    acc[0] += bflo(u.x); acc[1] += bfhi(u.x);
    acc[2] += bflo(u.y); acc[3] += bfhi(u.y);
    acc[4] += bflo(u.z); acc[5] += bfhi(u.z);
    acc[6] += bflo(u.w); acc[7] += bfhi(u.w);
  }
#pragma unroll
  for (int j = 0; j < 8; ++j) atomicAdd(&colsum[seg * 8 + j], acc[j]);
  __syncthreads();
  if (t < 128) atomicAdd(&pool[t], colsum[t]);
}

// ---------------- head ----------------
__global__ void k_head(const float* __restrict__ pool, const float* __restrict__ Wfc1,
                       const float* __restrict__ bfc1, const float* __restrict__ g,
                       const float* __restrict__ bb, const float* __restrict__ Wfc2,
                       const float* __restrict__ bfc2, float* __restrict__ out) {
  __shared__ float sm[128], s1[128], stats[2];
  int t = threadIdx.x;
  if (t < 128) sm[t] = pool[t] * (1.f / (float)N_NODES);
  __syncthreads();
  if (t < 128) {
    float a = bfc1[t];
    for (int k = 0; k < 128; ++k) a = fmaf(sm[k], Wfc1[k * 128 + t], a);
    s1[t] = a;
  }
  __syncthreads();
  if (t == 0) {
    float mu = 0.f;
    for (int k = 0; k < 128; ++k) mu += s1[k];
    mu *= (1.f / 128.f);
    float var = 0.f;
    for (int k = 0; k < 128; ++k) { float d = s1[k] - mu; var += d * d; }
    var *= (1.f / 128.f);
    stats[0] = mu; stats[1] = rsqrtf(var + EPS);
  }
  __syncthreads();
  if (t < 128) s1[t] = fmaxf((s1[t] - stats[0]) * stats[1] * g[t] + bb[t], 0.f);
  __syncthreads();
  if (t < OUT_F) {
    float a = bfc2[t];
    for (int k = 0; k < 128; ++k) a = fmaf(s1[k], Wfc2[k * OUT_F + t], a);
    out[t] = a;
  }
}

extern "C" void kernel_launch(void* const* d_in, const int* in_sizes, int n_in,
                              void* d_out, int out_size, void* d_ws, size_t ws_size,
                              hipStream_t stream) {
  const float* x      = (const float*)d_in[0];
  const int*   ei     = (const int*)d_in[1];
  const float* W_emb  = (const float*)d_in[2];
  const float* b_emb  = (const float*)d_in[3];
  const float* W_conv = (const float*)d_in[4];
  const float* b_conv = (const float*)d_in[5];
  const float* ln_g   = (const float*)d_in[6];
  const float* ln_b   = (const float*)d_in[7];
  const float* W_res  = (const float*)d_in[8];
  const float* b_res  = (const float*)d_in[9];
  const float* W_fc1  = (const float*)d_in[10];
  const float* b_fc1  = (const float*)d_in[11];
  const float* fcn_g  = (const float*)d_in[12];
  const float* fcn_b  = (const float*)d_in[13];
  const float* W_fc2  = (const float*)d_in[14];
  const float* b_fc2  = (const float*)d_in[15];
  float* out = (float*)d_out;

  char* p = (char*)d_ws;
  auto take = [&](size_t bytes) {
    char* r = p; p += (bytes + 255) & ~(size_t)255; return r;
  };
  unsigned short* bufA = (unsigned short*)take((size_t)N_NODES * H * 2);
  unsigned short* bufB = (unsigned short*)take((size_t)N_NODES * H * 2);
  unsigned short* bufC = (unsigned short*)take((size_t)N_NODES * H * 2);
  unsigned char*  ht8  = (unsigned char*)take((size_t)N_NODES * H);
  unsigned short* whiT = (unsigned short*)take((size_t)5 * H * H * 2);
  int*   deg8 = (int*)take((size_t)NXCD * N_NODES * 4);
  int*   degT = (int*)take(N_NODES * 4);
  int*   offs = (int*)take(N_NODES * 4);
  uint2* xp8  = (uint2*)take((size_t)N_NODES * 8);
  int*   parts= (int*)take(512 * 4);
  float* dinv = (float*)take(N_NODES * 4);
  unsigned short* ranks16 = (unsigned short*)take((size_t)NEDGES * 2);
  unsigned* csr = (unsigned*)take((size_t)NEDGES * 4);
  float* pool = (float*)take(128 * 4);

  (void)hipMemsetAsync(deg8, 0, (size_t)NXCD * N_NODES * 4, stream);
  (void)hipMemsetAsync(pool, 0, 128 * 4, stream);

  k_ws<<<WS_BLKS, 256, 0, stream>>>(W_conv, W_res, whiT);
  k_pre3<<<PRE3_BLKS, 256, 0, stream>>>(ei, deg8, ranks16, x, W_emb, b_emb, bufA,
                                        whiT + 0 * H * H, ht8);
  k_scan_a<<<NPARTS, 256, 0, stream>>>(deg8, degT, offs, xp8, parts, dinv);
  k_scan_b<<<1, 512, 0, stream>>>(parts, NPARTS);
  k_fill<<<FILL_BLKS, 256, 0, stream>>>(ei, ranks16, offs, xp8, parts, dinv, csr);

  // L0: res=h0=A -> h1=C
  k_agg<<<AGG_BLKS, 512, 0, stream>>>(ht8, bufA, dinv, offs, parts, degT, csr,
                                      b_conv + 0 * H, ln_g + 0 * H, ln_b + 0 * H, bufC);
  // L1: h1=C -> ht8 -> h2=A (res=C)
  k_mm<<<MM_BLKS, 256, 0, stream>>>(bufC, whiT + 1 * H * H, ht8);
  k_agg<<<AGG_BLKS, 512, 0, stream>>>(ht8, bufC, dinv, offs, parts, degT, csr,
                                      b_conv + 1 * H, ln_g + 1 * H, ln_b + 1 * H, bufA);
  // L2: h2=A; dual: ht8=A@W2, B=bf16(A@Wres+bres); agg -> h3=C (res=B)
  k_mmd<<<MM_BLKS, 256, 0, stream>>>(bufA, whiT + 2 * H * H, whiT + 4 * H * H,
                                     b_res, ht8, bufB);
  k_agg<<<AGG_BLKS, 512, 0, stream>>>(ht8, bufB, dinv, offs, parts, degT, csr,
                                      b_conv + 2 * H, ln_g + 2 * H, ln_b + 2 * H, bufC);
  // L3: h3=C -> ht8 -> h4=A (res=C)
  k_mm<<<MM_BLKS, 256, 0, stream>>>(bufC, whiT + 3 * H * H, ht8);
  k_agg<<<AGG_BLKS, 512, 0, stream>>>(ht8, bufC, dinv, offs, parts, degT, csr,
                                      b_conv + 3 * H, ln_g + 3 * H, ln_b + 3 * H, bufA);

  k_pool<<<256, 256, 0, stream>>>(bufA, pool);
  k_head<<<1, 256, 0, stream>>>(pool, W_fc1, b_fc1, fcn_g, fcn_b,
                                W_fc2, b_fc2, out);
}

// Round 4
// 445.719 us; speedup vs baseline: 1.3356x; 1.0944x over previous
//
#include <hip/hip_runtime.h>

constexpr int N_NODES = 100000;
constexpr int F_IN    = 32;
constexpr int H       = 128;
constexpr int OUT_F   = 200;
constexpr int NEDGES  = 1600000;
constexpr float EPS   = 1e-5f;

constexpr int WS_BLKS    = 80;                        // 5*128*128/1024
constexpr int TILE_BLKS  = (N_NODES + 63) / 64;       // 1563
constexpr int MM_BLKS    = TILE_BLKS * 2;             // 3126 (64r x 64c tiles)
constexpr int AGG_BLKS   = N_NODES / 32;              // 3125 (512 thr, 32 nodes, exact)

// ---- CSR build (r19): two-level LDS-binned, replaces the atomic histogram.
// Global atomic RMW w/ return measured at ~21 G/s (~8.7/cycle) device-wide in
// THREE configs (r0 device-scope, r2 per-XCD wg-scope, r3) -> 1.6M atomics
// == 77us, a hard serialization. This build uses 1.6M DS atomics (fast) and
// only ~76K global atomics (one per block x bucket).
constexpr int NB     = (N_NODES + 127) / 128;         // 782 buckets of 128 nodes
constexpr int BCAP   = 2560;                          // >=11 sigma above 2048 mean
constexpr int P1_EPT = 16, P1_THR = 512;
constexpr int P1_EPB = P1_THR * P1_EPT;               // 8192 edges/block
constexpr int P1_BLKS = (NEDGES + P1_EPB - 1) / P1_EPB;  // 196
constexpr int P2_IT  = BCAP / 256;                    // 10
constexpr int WQ_BLKS = NEDGES / 4 / 256;             // 1563 (exact: 1.6M/1024)

typedef __attribute__((ext_vector_type(8))) short  short8;
typedef __attribute__((ext_vector_type(4))) float  f32x4;
typedef __attribute__((ext_vector_type(2))) float  fv2;

__device__ __forceinline__ void fma4(float4& a, float s, const float4& w) {
  a.x = fmaf(s, w.x, a.x); a.y = fmaf(s, w.y, a.y);
  a.z = fmaf(s, w.z, a.z); a.w = fmaf(s, w.w, a.w);
}

__device__ __forceinline__ unsigned short f2bf(float f) {  // RNE
  union { float f; unsigned u; } v; v.f = f;
  unsigned r = v.u + 0x7fffu + ((v.u >> 16) & 1u);
  return (unsigned short)(r >> 16);
}
__device__ __forceinline__ float bflo(unsigned u) { return __uint_as_float(u << 16); }
__device__ __forceinline__ float bfhi(unsigned u) { return __uint_as_float(u & 0xffff0000u); }
__device__ __forceinline__ unsigned pack2(float lo, float hi) {
  return (unsigned)f2bf(lo) | ((unsigned)f2bf(hi) << 16);
}
__device__ __forceinline__ void st_bf4(unsigned short* p, float4 v) {
  uint2 o; o.x = pack2(v.x, v.y); o.y = pack2(v.z, v.w);
  *(uint2*)p = o;
}

// ---------------- fp8 e4m3fn helpers ----------------
#if __has_builtin(__builtin_amdgcn_cvt_pk_f32_fp8) && __has_builtin(__builtin_amdgcn_cvt_pk_fp8_f32)
#define HAVE_FP8_CVT 1
#endif

#ifndef HAVE_FP8_CVT
__device__ __forceinline__ float fp8_dec1(unsigned b) {
  unsigned s = (b >> 7) & 1u, E = (b >> 3) & 15u, m = b & 7u;
  float v;
  if (E) {
    union { unsigned u; float f; } t;
    t.u = (s << 31) | ((E + 120u) << 23) | (m << 20);
    v = t.f;
  } else {
    v = (s ? -1.f : 1.f) * (float)m * 0.001953125f;
  }
  return v;
}
#endif

template <bool HI>
__device__ __forceinline__ fv2 fp8x2(unsigned u) {
#ifdef HAVE_FP8_CVT
  return __builtin_amdgcn_cvt_pk_f32_fp8((int)u, HI);
#else
  unsigned p = HI ? (u >> 16) : u;
  fv2 r; r.x = fp8_dec1(p & 0xffu); r.y = fp8_dec1((p >> 8) & 0xffu);
  return r;
#endif
}

__device__ __forceinline__ unsigned char f32_to_fp8(float f) {
#ifdef HAVE_FP8_CVT
  return (unsigned char)(__builtin_amdgcn_cvt_pk_fp8_f32(f, f, 0, false) & 0xff);
#else
  union { float f; unsigned u; } t; t.f = f;
  unsigned s = t.u >> 31;
  float a = fabsf(f);
  if (a > 448.f) a = 448.f;
  t.f = a;
  int e = (int)((t.u >> 23) & 0xff) - 127;
  unsigned char r;
  if (a == 0.f) {
    r = 0;
  } else if (e >= -6) {
    unsigned m = t.u & 0x7fffffu;
    unsigned keep = m >> 20, rest = m & 0xfffffu;
    keep += (rest > 0x80000u) || (rest == 0x80000u && (keep & 1u));
    int E = e + 7;
    if (keep == 8u) { keep = 0u; E += 1; }
    if (E >= 16) { E = 15; keep = 6u; }
    r = (unsigned char)((E << 3) | keep);
  } else {
    int mi = (int)(a * 512.f + 0.5f);
    r = (mi > 7) ? (unsigned char)(1u << 3) : (unsigned char)mi;
  }
  return (unsigned char)(r | (s << 7));
#endif
}

// ---------------- k_ws: W -> bf16 transposed ----------------
__global__ void k_ws(const float* __restrict__ W_conv,
                     const float* __restrict__ W_res,
                     unsigned short* __restrict__ whiT) {
  int base = blockIdx.x * 1024;
#pragma unroll
  for (int j = 0; j < 4; ++j) {
    int idx = base + j * 256 + threadIdx.x;
    if (idx < 5 * H * H) {
      int m = idx >> 14, rr = idx & 16383;
      int k = rr >> 7, n = rr & 127;
      const float* src = (m < 4) ? (W_conv + m * H * H) : W_res;
      whiT[m * H * H + n * H + k] = f2bf(src[k * H + n]);
    }
  }
}

// mm from LDS tile: 64 rows x 128 cols, wave = 32r x 64c (B frags hoisted)
__device__ __forceinline__ void mm_lds_fp8(const unsigned short* sA,
                                           const unsigned short* __restrict__ WT,
                                           int n0, int t,
                                           unsigned char* __restrict__ htOut) {
  int wave = t >> 6, lane = t & 63;
  int wr = wave >> 1, wc = wave & 1;
  int m = lane & 15, quad = (lane >> 4) & 3;
  short8 bh[4][4];
#pragma unroll
  for (int q = 0; q < 4; ++q)
#pragma unroll
    for (int ct = 0; ct < 4; ++ct) {
      int n = wc * 64 + ct * 16 + m;
      bh[q][ct] = *(const short8*)(WT + n * H + q * 32 + quad * 8);
    }
  f32x4 acc[2][4];
#pragma unroll
  for (int i = 0; i < 2; ++i)
#pragma unroll
    for (int j = 0; j < 4; ++j) acc[i][j] = (f32x4){0.f, 0.f, 0.f, 0.f};
#pragma unroll
  for (int q = 0; q < 4; ++q) {
    short8 ah[2];
#pragma unroll
    for (int rt = 0; rt < 2; ++rt)
      ah[rt] = *(const short8*)(sA + (wr * 32 + rt * 16 + m) * 136 + q * 32 + quad * 8);
#pragma unroll
    for (int rt = 0; rt < 2; ++rt)
#pragma unroll
      for (int ct = 0; ct < 4; ++ct)
        acc[rt][ct] = __builtin_amdgcn_mfma_f32_16x16x32_bf16(ah[rt], bh[q][ct], acc[rt][ct], 0, 0, 0);
  }
#pragma unroll
  for (int rt = 0; rt < 2; ++rt)
#pragma unroll
    for (int ct = 0; ct < 4; ++ct) {
      int col = wc * 64 + ct * 16 + m;
#pragma unroll
      for (int rr = 0; rr < 4; ++rr) {
        int gn = n0 + wr * 32 + rt * 16 + quad * 4 + rr;
        if (gn < N_NODES) htOut[(size_t)gn * H + col] = f32_to_fp8(acc[rt][ct][rr]);
      }
    }
}

// ---------------- k_embed: embed 64-node tile -> LDS -> mm W0 ----------------
__global__ __launch_bounds__(256) void k_embed(
    const float* __restrict__ x, const float* __restrict__ W_emb,
    const float* __restrict__ b_emb, unsigned short* __restrict__ h,
    const unsigned short* __restrict__ W0T, unsigned char* __restrict__ ht8) {
  __shared__ __align__(16) char smem[25600];
  int t = threadIdx.x;
  int n0 = blockIdx.x * 64;
  float* sW = (float*)smem;
  float* sX = sW + 4096;
  unsigned short* sH = (unsigned short*)smem;
#pragma unroll
  for (int p = 0; p < 4; ++p)
    ((float4*)sW)[t + p * 256] = ((const float4*)W_emb)[t + p * 256];
#pragma unroll
  for (int p = 0; p < 2; ++p) {
    int fi = t * 2 + p;
    int row = fi >> 3, k4 = (fi & 7) * 4;
    int gn = n0 + row; if (gn >= N_NODES) gn = N_NODES - 1;
    *(float4*)(sX + row * 36 + k4) = *(const float4*)(x + (size_t)gn * F_IN + k4);
  }
  __syncthreads();
  // conflict-free sW reads: col0 = (t&3)*4 -> banks {0,4,8,12}(+16i)
  int nr = t >> 2, col0 = (t & 3) * 4;
  float4 acc[8];
#pragma unroll
  for (int i = 0; i < 8; ++i) acc[i] = make_float4(0.f, 0.f, 0.f, 0.f);
#pragma unroll 4
  for (int k = 0; k < F_IN; ++k) {
    float xv = sX[nr * 36 + k];
    const float* wp = sW + k * H + col0;
#pragma unroll
    for (int i = 0; i < 8; ++i) fma4(acc[i], xv, *(const float4*)(wp + i * 16));
  }
#pragma unroll
  for (int i = 0; i < 8; ++i) {
    float4 bv = *(const float4*)(b_emb + col0 + i * 16);
    acc[i].x += bv.x; acc[i].y += bv.y; acc[i].z += bv.z; acc[i].w += bv.w;
  }
  __syncthreads();  // done reading sW/sX; reuse as sH
  int node = n0 + nr;
  unsigned short* hr = h + (size_t)node * H + col0;
#pragma unroll
  for (int i = 0; i < 8; ++i) {
    st_bf4(sH + nr * 136 + col0 + i * 16, acc[i]);
    if (node < N_NODES) st_bf4(hr + i * 16, acc[i]);
  }
  __syncthreads();
  mm_lds_fp8(sH, W0T, n0, t, ht8);
}

// ---------------- k_p1: bucket-bin edges (LDS hist, 76K global atomics) ----
__global__ __launch_bounds__(512) void k_p1(const int* __restrict__ ei,
                                            int* __restrict__ bcnt,
                                            unsigned* __restrict__ bscr) {
  __shared__ int hist[NB];
  __shared__ int hbase[NB];
  int t = threadIdx.x;
  for (int i = t; i < NB; i += 512) hist[i] = 0;
  __syncthreads();
  int e0 = blockIdx.x * P1_EPB;
  unsigned pk[P1_EPT]; int br[P1_EPT];
#pragma unroll
  for (int k = 0; k < P1_EPT; ++k) {
    int e = e0 + k * 512 + t;
    if (e < NEDGES) {
      int src = ei[e];
      int dst = ei[NEDGES + e];
      int b = dst >> 7;
      pk[k] = ((unsigned)src << 7) | (unsigned)(dst & 127);
      int r = atomicAdd(&hist[b], 1);        // DS atomic w/ return
      br[k] = (b << 13) | r;                 // r < 8192 always
    } else {
      br[k] = -1; pk[k] = 0;
    }
  }
  __syncthreads();
  for (int i = t; i < NB; i += 512) {
    int c = hist[i];
    hbase[i] = c ? atomicAdd(&bcnt[i], c) : 0;  // global atomic (sparse)
  }
  __syncthreads();
#pragma unroll
  for (int k = 0; k < P1_EPT; ++k) {
    if (br[k] >= 0) {
      int b = br[k] >> 13, r = br[k] & 8191;
      int pos = hbase[b] + r;
      if (pos < BCAP) bscr[(size_t)b * BCAP + pos] = pk[k];  // safety clamp
    }
  }
}

// ---------------- k_scanbc: exclusive scan of bucket counts ----------------
__global__ void k_scanbc(const int* __restrict__ bcnt, int* __restrict__ bbase) {
  __shared__ int s[1024];
  int t = threadIdx.x;
  int d = (t < NB) ? bcnt[t] : 0;
  s[t] = d;
  __syncthreads();
#pragma unroll
  for (int off = 1; off < 1024; off <<= 1) {
    int v = (t >= off) ? s[t - off] : 0;
    __syncthreads();
    s[t] += v;
    __syncthreads();
  }
  if (t < NB) bbase[t] = s[t] - d;
}

// ---------------- k_p2: per-bucket deg/rank (DS atomics) + csr scatter ------
__global__ __launch_bounds__(256) void k_p2(const unsigned* __restrict__ bscr,
                                            const int* __restrict__ bcnt,
                                            const int* __restrict__ bbase,
                                            int* __restrict__ degT,
                                            int* __restrict__ offs,
                                            float* __restrict__ dinv,
                                            unsigned* __restrict__ csr) {
  __shared__ int dl[128], sc[128];
  int b = blockIdx.x, t = threadIdx.x;
  if (t < 128) dl[t] = 0;
  __syncthreads();
  int n = min(bcnt[b], BCAP);
  int base = bbase[b];
  const unsigned* seg = bscr + (size_t)b * BCAP;
  unsigned pk[P2_IT]; unsigned short rr[P2_IT];
#pragma unroll
  for (int k = 0; k < P2_IT; ++k) {
    int i = k * 256 + t;
    if (i < n) {
      unsigned p = seg[i];
      pk[k] = p;
      rr[k] = (unsigned short)atomicAdd(&dl[p & 127u], 1);
    } else pk[k] = 0xffffffffu;   // payload < 2^24, sentinel safe
  }
  __syncthreads();
  if (t < 128) sc[t] = dl[t];
  __syncthreads();
#pragma unroll
  for (int off = 1; off < 128; off <<= 1) {
    int v = (t >= off && t < 128) ? sc[t - off] : 0;
    __syncthreads();
    if (t < 128) sc[t] += v;
    __syncthreads();
  }
  if (t < 128) {
    int node = b * 128 + t;
    if (node < N_NODES) {
      int d = dl[t];
      degT[node] = d;
      dinv[node] = rsqrtf((float)(d + 1));
      offs[node] = base + sc[t] - d;      // absolute exclusive offset
    }
  }
  __syncthreads();
#pragma unroll
  for (int k = 0; k < P2_IT; ++k) {
    if (pk[k] != 0xffffffffu) {
      unsigned p = pk[k];
      unsigned dlo = p & 127u;
      int pos = base + (sc[dlo] - dl[dlo]) + (int)rr[k];
      csr[pos] = (p >> 7) << 15;          // src<<15; w OR'd in k_wq
    }
  }
}

// ---------------- k_wq: OR quantized dinv[src] into csr entries ------------
__global__ __launch_bounds__(256) void k_wq(unsigned* __restrict__ csr,
                                            const float* __restrict__ dinv) {
  int i = (blockIdx.x * 256 + threadIdx.x) * 4;
  if (i < NEDGES) {
    uint4 e = *(uint4*)(csr + i);
    e.x |= (unsigned)(dinv[e.x >> 15] * 32767.f + 0.5f);
    e.y |= (unsigned)(dinv[e.y >> 15] * 32767.f + 0.5f);
    e.z |= (unsigned)(dinv[e.z >> 15] * 32767.f + 0.5f);
    e.w |= (unsigned)(dinv[e.w >> 15] * 32767.f + 0.5f);
    *(uint4*)(csr + i) = e;
  }
}

// ---------------- mm core for layers 1-3 (global A) ----------------
struct MMAcc { f32x4 a[2][2]; };

__device__ __forceinline__ MMAcc mm_core(const unsigned short* __restrict__ A,
                                         const unsigned short* __restrict__ WhiT,
                                         int n0, int c0, int t,
                                         unsigned short* sA) {
  int wave = t >> 6, lane = t & 63;
  int wr = wave >> 1, wc = wave & 1;
  int m = lane & 15, quad = (lane >> 4) & 3;
  short8 bh[4][2];
#pragma unroll
  for (int q = 0; q < 4; ++q)
#pragma unroll
    for (int ct = 0; ct < 2; ++ct) {
      int n = c0 + wc * 32 + ct * 16 + m;
      bh[q][ct] = *(const short8*)(WhiT + n * H + q * 32 + quad * 8);
    }
#pragma unroll
  for (int p = 0; p < 4; ++p) {
    int fi = t + p * 256;
    int row = fi >> 4, c8 = (fi & 15) * 8;
    int gn = n0 + row; if (gn >= N_NODES) gn = N_NODES - 1;
    *(uint4*)(sA + row * 136 + c8) = *(const uint4*)(A + (size_t)gn * H + c8);
  }
  __syncthreads();
  MMAcc r;
#pragma unroll
  for (int i = 0; i < 2; ++i)
#pragma unroll
    for (int j = 0; j < 2; ++j) r.a[i][j] = (f32x4){0.f, 0.f, 0.f, 0.f};
#pragma unroll
  for (int q = 0; q < 4; ++q) {
    short8 ah[2];
#pragma unroll
    for (int rt = 0; rt < 2; ++rt)
      ah[rt] = *(const short8*)(sA + (wr * 32 + rt * 16 + m) * 136 + q * 32 + quad * 8);
#pragma unroll
    for (int rt = 0; rt < 2; ++rt)
#pragma unroll
      for (int ct = 0; ct < 2; ++ct)
        r.a[rt][ct] = __builtin_amdgcn_mfma_f32_16x16x32_bf16(ah[rt], bh[q][ct], r.a[rt][ct], 0, 0, 0);
  }
  return r;
}

__device__ __forceinline__ void mm_store_fp8(const MMAcc& r, unsigned char* ht8,
                                             int n0, int c0, int t) {
  int wave = t >> 6, lane = t & 63;
  int wr = wave >> 1, wc = wave & 1;
  int m = lane & 15, quad = (lane >> 4) & 3;
#pragma unroll
  for (int rt = 0; rt < 2; ++rt)
#pragma unroll
    for (int ct = 0; ct < 2; ++ct) {
      int col = c0 + wc * 32 + ct * 16 + m;
#pragma unroll
      for (int rr = 0; rr < 4; ++rr) {
        int gn = n0 + wr * 32 + rt * 16 + quad * 4 + rr;
        if (gn < N_NODES) ht8[(size_t)gn * H + col] = f32_to_fp8(r.a[rt][ct][rr]);
      }
    }
}

__global__ __launch_bounds__(256) void k_mm(const unsigned short* __restrict__ A,
                                            const unsigned short* __restrict__ WhiT,
                                            unsigned char* __restrict__ ht8) {
  __shared__ __align__(16) unsigned short sA[64 * 136];
  int j = blockIdx.x;
  int n0 = (j >> 1) * 64, c0 = (j & 1) * 64;
  MMAcc r = mm_core(A, WhiT, n0, c0, threadIdx.x, sA);
  mm_store_fp8(r, ht8, n0, c0, threadIdx.x);
}

// layer-2 dual GEMM
__global__ __launch_bounds__(256) void k_mmd(const unsigned short* __restrict__ A,
    const unsigned short* __restrict__ WcT, const unsigned short* __restrict__ WrT,
    const float* __restrict__ bias,
    unsigned char* __restrict__ ht8, unsigned short* __restrict__ resb) {
  __shared__ __align__(16) unsigned short sA[64 * 136];
  int t = threadIdx.x;
  int j = blockIdx.x;
  int n0 = (j >> 1) * 64, c0 = (j & 1) * 64;
  int wave = t >> 6, lane = t & 63;
  int wr = wave >> 1, wc = wave & 1;
  int m = lane & 15, quad = (lane >> 4) & 3;
  short8 bhc[4][2], bhr[4][2];
#pragma unroll
  for (int q = 0; q < 4; ++q)
#pragma unroll
    for (int ct = 0; ct < 2; ++ct) {
      int n = c0 + wc * 32 + ct * 16 + m;
      bhc[q][ct] = *(const short8*)(WcT + n * H + q * 32 + quad * 8);
      bhr[q][ct] = *(const short8*)(WrT + n * H + q * 32 + quad * 8);
    }
#pragma unroll
  for (int p = 0; p < 4; ++p) {
    int fi = t + p * 256;
    int row = fi >> 4, c8 = (fi & 15) * 8;
    int gn = n0 + row; if (gn >= N_NODES) gn = N_NODES - 1;
    *(uint4*)(sA + row * 136 + c8) = *(const uint4*)(A + (size_t)gn * H + c8);
  }
  __syncthreads();
  f32x4 accC[2][2], accR[2][2];
#pragma unroll
  for (int i = 0; i < 2; ++i)
#pragma unroll
    for (int jj = 0; jj < 2; ++jj) {
      accC[i][jj] = (f32x4){0.f, 0.f, 0.f, 0.f};
      accR[i][jj] = (f32x4){0.f, 0.f, 0.f, 0.f};
    }
#pragma unroll
  for (int q = 0; q < 4; ++q) {
    short8 ah[2];
#pragma unroll
    for (int rt = 0; rt < 2; ++rt)
      ah[rt] = *(const short8*)(sA + (wr * 32 + rt * 16 + m) * 136 + q * 32 + quad * 8);
#pragma unroll
    for (int rt = 0; rt < 2; ++rt)
#pragma unroll
      for (int ct = 0; ct < 2; ++ct) {
        accC[rt][ct] = __builtin_amdgcn_mfma_f32_16x16x32_bf16(ah[rt], bhc[q][ct], accC[rt][ct], 0, 0, 0);
        accR[rt][ct] = __builtin_amdgcn_mfma_f32_16x16x32_bf16(ah[rt], bhr[q][ct], accR[rt][ct], 0, 0, 0);
      }
  }
#pragma unroll
  for (int rt = 0; rt < 2; ++rt)
#pragma unroll
    for (int ct = 0; ct < 2; ++ct) {
      int col = c0 + wc * 32 + ct * 16 + m;
      float bv = bias[col];
#pragma unroll
      for (int rr = 0; rr < 4; ++rr) {
        int gn = n0 + wr * 32 + rt * 16 + quad * 4 + rr;
        if (gn < N_NODES) {
          ht8[(size_t)gn * H + col]  = f32_to_fp8(accC[rt][ct][rr]);
          resb[(size_t)gn * H + col] = f2bf(accR[rt][ct][rr] + bv);
        }
      }
    }
}

// ---------------- aggregate(fp8 ht) + bias + LN + relu + residual(bf16) ----
// r18 structure: one node per 16-lane group (4 nodes/wave). r19: offs is
// absolute (parts removed).
__device__ __forceinline__ void agg_round8(const unsigned char* __restrict__ ht8,
                                           unsigned flo, int gbase, int e0,
                                           int s, float w, fv2* acc2) {
  uint2 uu[8]; float ww[8];
#pragma unroll
  for (int jj = 0; jj < 8; ++jj) {
    int ss = __shfl(s, gbase + e0 + jj, 64);
    ww[jj] = __shfl(w, gbase + e0 + jj, 64);
    uu[jj] = *(const uint2*)(ht8 + (((unsigned)ss << 7) | flo));
  }
#pragma unroll
  for (int jj = 0; jj < 8; ++jj) {
    float we = ww[jj];
    fv2 we2 = {we, we};
    acc2[0] += we2 * fp8x2<false>(uu[jj].x);
    acc2[1] += we2 * fp8x2<true>(uu[jj].x);
    acc2[2] += we2 * fp8x2<false>(uu[jj].y);
    acc2[3] += we2 * fp8x2<true>(uu[jj].y);
  }
}

__global__ __launch_bounds__(512) void k_agg(
    const unsigned char* __restrict__ ht8, const unsigned short* __restrict__ res,
    const float* __restrict__ dinv, const int* __restrict__ offs,
    const int* __restrict__ degT, const unsigned* __restrict__ csr,
    const float* __restrict__ bias, const float* __restrict__ lng,
    const float* __restrict__ lnb, unsigned short* __restrict__ hout) {
  int t = threadIdx.x;
  int fl = t & 15;
  int gbase = t & 48;                    // group base lane within wave
  int node = blockIdx.x * 32 + (t >> 4); // exact: 3125*32 == 100000
  unsigned flo = (unsigned)fl * 8u;
  int start = offs[node], cnt = degT[node];
  float di = dinv[node];
  fv2 acc2[4];
  {
    uint2 u = *(const uint2*)(ht8 + (((unsigned)node << 7) | flo));
    float sw = di * di;
    fv2 sw2 = {sw, sw};
    acc2[0] = sw2 * fp8x2<false>(u.x);
    acc2[1] = sw2 * fp8x2<true>(u.x);
    acc2[2] = sw2 * fp8x2<false>(u.y);
    acc2[3] = sw2 * fp8x2<true>(u.y);
  }
  float ddq = di * (1.f / 32767.f);
  for (int b0 = 0; b0 < cnt; b0 += 16) {
    int m = min(16, cnt - b0);
    int s = node; float w = 0.f;
    if (fl < m) {
      unsigned ev = csr[start + b0 + fl];
      s = (int)(ev >> 15);
      w = (float)(ev & 32767u) * ddq;
    }
    agg_round8(ht8, flo, gbase, 0, s, w, acc2);
    if (m > 8) agg_round8(ht8, flo, gbase, 8, s, w, acc2);
  }
  float acc[8] = {acc2[0].x, acc2[0].y, acc2[1].x, acc2[1].y,
                  acc2[2].x, acc2[2].y, acc2[3].x, acc2[3].y};
  float4 b0v = *(const float4*)(bias + fl * 8);
  float4 b1v = *(const float4*)(bias + fl * 8 + 4);
  acc[0] += b0v.x; acc[1] += b0v.y; acc[2] += b0v.z; acc[3] += b0v.w;
  acc[4] += b1v.x; acc[5] += b1v.y; acc[6] += b1v.z; acc[7] += b1v.w;
  float sl = ((acc[0] + acc[1]) + (acc[2] + acc[3])) +
             ((acc[4] + acc[5]) + (acc[6] + acc[7]));
#pragma unroll
  for (int mk = 1; mk <= 8; mk <<= 1) sl += __shfl_xor(sl, mk, 16);
  float mu = sl * (1.f / 128.f);
  float d[8];
  float vl = 0.f;
#pragma unroll
  for (int j = 0; j < 8; ++j) { d[j] = acc[j] - mu; vl = fmaf(d[j], d[j], vl); }
#pragma unroll
  for (int mk = 1; mk <= 8; mk <<= 1) vl += __shfl_xor(vl, mk, 16);
  float rs = rsqrtf(vl * (1.f / 128.f) + EPS);
  float4 g0 = *(const float4*)(lng + fl * 8);
  float4 g1 = *(const float4*)(lng + fl * 8 + 4);
  float4 be0 = *(const float4*)(lnb + fl * 8);
  float4 be1 = *(const float4*)(lnb + fl * 8 + 4);
  uint4 rv = *(const uint4*)(res + (size_t)node * 128 + fl * 8);
  float o0 = fmaxf(fmaf(d[0] * rs, g0.x, be0.x), 0.f) + bflo(rv.x);
  float o1 = fmaxf(fmaf(d[1] * rs, g0.y, be0.y), 0.f) + bfhi(rv.x);
  float o2 = fmaxf(fmaf(d[2] * rs, g0.z, be0.z), 0.f) + bflo(rv.y);
  float o3 = fmaxf(fmaf(d[3] * rs, g0.w, be0.w), 0.f) + bfhi(rv.y);
  float o4 = fmaxf(fmaf(d[4] * rs, g1.x, be1.x), 0.f) + bflo(rv.z);
  float o5 = fmaxf(fmaf(d[5] * rs, g1.y, be1.y), 0.f) + bfhi(rv.z);
  float o6 = fmaxf(fmaf(d[6] * rs, g1.z, be1.z), 0.f) + bflo(rv.w);
  float o7 = fmaxf(fmaf(d[7] * rs, g1.w, be1.w), 0.f) + bfhi(rv.w);
  uint4 ov;
  ov.x = pack2(o0, o1); ov.y = pack2(o2, o3);
  ov.z = pack2(o4, o5); ov.w = pack2(o6, o7);
  *(uint4*)(hout + (size_t)node * 128 + fl * 8) = ov;
}

// ---------------- mean pool (bf16 h, vectorized uint4 loads) ----------------
__global__ __launch_bounds__(256) void k_pool(const unsigned short* __restrict__ h,
                                              float* __restrict__ pool) {
  __shared__ float colsum[128];
  int t = threadIdx.x;
  if (t < 128) colsum[t] = 0.f;
  __syncthreads();
  int lr = t >> 4, seg = t & 15;   // 16 rows/pass, 16 x uint4 per row
  float acc[8] = {0.f, 0.f, 0.f, 0.f, 0.f, 0.f, 0.f, 0.f};
  for (int n = blockIdx.x * 16 + lr; n < N_NODES; n += gridDim.x * 16) {
    uint4 u = *(const uint4*)(h + (size_t)n * H + seg * 8);
    acc[0] += bflo(u.x); acc[1] += bfhi(u.x);
    acc[2] += bflo(u.y); acc[3] += bfhi(u.y);
    acc[4] += bflo(u.z); acc[5] += bfhi(u.z);
    acc[6] += bflo(u.w); acc[7] += bfhi(u.w);
  }
#pragma unroll
  for (int j = 0; j < 8; ++j) atomicAdd(&colsum[seg * 8 + j], acc[j]);
  __syncthreads();
  if (t < 128) atomicAdd(&pool[t], colsum[t]);
}

// ---------------- head ----------------
__global__ void k_head(const float* __restrict__ pool, const float* __restrict__ Wfc1,
                       const float* __restrict__ bfc1, const float* __restrict__ g,
                       const float* __restrict__ bb, const float* __restrict__ Wfc2,
                       const float* __restrict__ bfc2, float* __restrict__ out) {
  __shared__ float sm[128], s1[128], stats[2];
  int t = threadIdx.x;
  if (t < 128) sm[t] = pool[t] * (1.f / (float)N_NODES);
  __syncthreads();
  if (t < 128) {
    float a = bfc1[t];
    for (int k = 0; k < 128; ++k) a = fmaf(sm[k], Wfc1[k * 128 + t], a);
    s1[t] = a;
  }
  __syncthreads();
  if (t == 0) {
    float mu = 0.f;
    for (int k = 0; k < 128; ++k) mu += s1[k];
    mu *= (1.f / 128.f);
    float var = 0.f;
    for (int k = 0; k < 128; ++k) { float d = s1[k] - mu; var += d * d; }
    var *= (1.f / 128.f);
    stats[0] = mu; stats[1] = rsqrtf(var + EPS);
  }
  __syncthreads();
  if (t < 128) s1[t] = fmaxf((s1[t] - stats[0]) * stats[1] * g[t] + bb[t], 0.f);
  __syncthreads();
  if (t < OUT_F) {
    float a = bfc2[t];
    for (int k = 0; k < 128; ++k) a = fmaf(s1[k], Wfc2[k * OUT_F + t], a);
    out[t] = a;
  }
}

extern "C" void kernel_launch(void* const* d_in, const int* in_sizes, int n_in,
                              void* d_out, int out_size, void* d_ws, size_t ws_size,
                              hipStream_t stream) {
  const float* x      = (const float*)d_in[0];
  const int*   ei     = (const int*)d_in[1];
  const float* W_emb  = (const float*)d_in[2];
  const float* b_emb  = (const float*)d_in[3];
  const float* W_conv = (const float*)d_in[4];
  const float* b_conv = (const float*)d_in[5];
  const float* ln_g   = (const float*)d_in[6];
  const float* ln_b   = (const float*)d_in[7];
  const float* W_res  = (const float*)d_in[8];
  const float* b_res  = (const float*)d_in[9];
  const float* W_fc1  = (const float*)d_in[10];
  const float* b_fc1  = (const float*)d_in[11];
  const float* fcn_g  = (const float*)d_in[12];
  const float* fcn_b  = (const float*)d_in[13];
  const float* W_fc2  = (const float*)d_in[14];
  const float* b_fc2  = (const float*)d_in[15];
  float* out = (float*)d_out;

  char* p = (char*)d_ws;
  auto take = [&](size_t bytes) {
    char* r = p; p += (bytes + 255) & ~(size_t)255; return r;
  };
  unsigned short* bufA = (unsigned short*)take((size_t)N_NODES * H * 2);
  unsigned short* bufB = (unsigned short*)take((size_t)N_NODES * H * 2);
  unsigned short* bufC = (unsigned short*)take((size_t)N_NODES * H * 2);
  unsigned char*  ht8  = (unsigned char*)take((size_t)N_NODES * H);
  unsigned short* whiT = (unsigned short*)take((size_t)5 * H * H * 2);
  int*   degT = (int*)take(N_NODES * 4);
  int*   offs = (int*)take(N_NODES * 4);
  float* dinv = (float*)take(N_NODES * 4);
  int*   bcnt = (int*)take(NB * 4);
  int*   bbase= (int*)take(NB * 4);
  unsigned* bscr = (unsigned*)take((size_t)NB * BCAP * 4);
  unsigned* csr  = (unsigned*)take((size_t)NEDGES * 4);
  float* pool = (float*)take(128 * 4);

  (void)hipMemsetAsync(bcnt, 0, NB * 4, stream);
  (void)hipMemsetAsync(pool, 0, 128 * 4, stream);

  k_ws<<<WS_BLKS, 256, 0, stream>>>(W_conv, W_res, whiT);
  k_p1<<<P1_BLKS, P1_THR, 0, stream>>>(ei, bcnt, bscr);
  k_scanbc<<<1, 1024, 0, stream>>>(bcnt, bbase);
  k_p2<<<NB, 256, 0, stream>>>(bscr, bcnt, bbase, degT, offs, dinv, csr);
  k_wq<<<WQ_BLKS, 256, 0, stream>>>(csr, dinv);
  k_embed<<<TILE_BLKS, 256, 0, stream>>>(x, W_emb, b_emb, bufA,
                                         whiT + 0 * H * H, ht8);

  // L0: res=h0=A -> h1=C
  k_agg<<<AGG_BLKS, 512, 0, stream>>>(ht8, bufA, dinv, offs, degT, csr,
                                      b_conv + 0 * H, ln_g + 0 * H, ln_b + 0 * H, bufC);
  // L1: h1=C -> ht8 -> h2=A (res=C)
  k_mm<<<MM_BLKS, 256, 0, stream>>>(bufC, whiT + 1 * H * H, ht8);
  k_agg<<<AGG_BLKS, 512, 0, stream>>>(ht8, bufC, dinv, offs, degT, csr,
                                      b_conv + 1 * H, ln_g + 1 * H, ln_b + 1 * H, bufA);
  // L2: h2=A; dual: ht8=A@W2, B=bf16(A@Wres+bres); agg -> h3=C (res=B)
  k_mmd<<<MM_BLKS, 256, 0, stream>>>(bufA, whiT + 2 * H * H, whiT + 4 * H * H,
                                     b_res, ht8, bufB);
  k_agg<<<AGG_BLKS, 512, 0, stream>>>(ht8, bufB, dinv, offs, degT, csr,
                                      b_conv + 2 * H, ln_g + 2 * H, ln_b + 2 * H, bufC);
  // L3: h3=C -> ht8 -> h4=A (res=C)
  k_mm<<<MM_BLKS, 256, 0, stream>>>(bufC, whiT + 3 * H * H, ht8);
  k_agg<<<AGG_BLKS, 512, 0, stream>>>(ht8, bufC, dinv, offs, degT, csr,
                                      b_conv + 3 * H, ln_g + 3 * H, ln_b + 3 * H, bufA);

  k_pool<<<256, 256, 0, stream>>>(bufA, pool);
  k_head<<<1, 256, 0, stream>>>(pool, W_fc1, b_fc1, fcn_g, fcn_b,
                                W_fc2, b_fc2, out);
}

// Round 5
// 434.787 us; speedup vs baseline: 1.3692x; 1.0251x over previous
//
#include <hip/hip_runtime.h>

constexpr int N_NODES = 100000;
constexpr int F_IN    = 32;
constexpr int H       = 128;
constexpr int OUT_F   = 200;
constexpr int NEDGES  = 1600000;
constexpr float EPS   = 1e-5f;

constexpr int TILE_BLKS  = (N_NODES + 63) / 64;       // 1563
constexpr int MM_BLKS    = TILE_BLKS;                 // r20: full-width 64x128 tiles
constexpr int MMD_BLKS   = TILE_BLKS * 2;             // k_mmd keeps 64x64 split (VGPR)
constexpr int AGG_BLKS   = N_NODES / 32;              // 3125 (512 thr, 32 nodes, exact)

// ---- CSR build (r19): two-level LDS-binned. Global atomic RMW w/ return
// measured ~21 G/s device-wide regardless of scope/slicing (r0/r2/r3) ->
// 1.6M atomics == 77us. This build: 1.6M DS atomics + ~76K global atomics.
constexpr int NB     = (N_NODES + 127) / 128;         // 782 buckets of 128 nodes
constexpr int BCAP   = 2560;                          // >=11 sigma above 2048 mean
constexpr int P1_EPT = 16, P1_THR = 512;
constexpr int P1_EPB = P1_THR * P1_EPT;               // 8192 edges/block
constexpr int P1_BLKS = (NEDGES + P1_EPB - 1) / P1_EPB;  // 196
constexpr int WS_BLKS = 40;                           // r20: fused into k_p1 (512 thr)
constexpr int P2_IT  = BCAP / 256;                    // 10
constexpr int WQ_BLKS = NEDGES / 4 / 256;             // 1563

typedef __attribute__((ext_vector_type(8))) short  short8;
typedef __attribute__((ext_vector_type(4))) float  f32x4;
typedef __attribute__((ext_vector_type(2))) float  fv2;

__device__ __forceinline__ void fma4(float4& a, float s, const float4& w) {
  a.x = fmaf(s, w.x, a.x); a.y = fmaf(s, w.y, a.y);
  a.z = fmaf(s, w.z, a.z); a.w = fmaf(s, w.w, a.w);
}

__device__ __forceinline__ unsigned short f2bf(float f) {  // RNE
  union { float f; unsigned u; } v; v.f = f;
  unsigned r = v.u + 0x7fffu + ((v.u >> 16) & 1u);
  return (unsigned short)(r >> 16);
}
__device__ __forceinline__ float bflo(unsigned u) { return __uint_as_float(u << 16); }
__device__ __forceinline__ float bfhi(unsigned u) { return __uint_as_float(u & 0xffff0000u); }
__device__ __forceinline__ unsigned pack2(float lo, float hi) {
  return (unsigned)f2bf(lo) | ((unsigned)f2bf(hi) << 16);
}
__device__ __forceinline__ void st_bf4(unsigned short* p, float4 v) {
  uint2 o; o.x = pack2(v.x, v.y); o.y = pack2(v.z, v.w);
  *(uint2*)p = o;
}

// ---------------- fp8 e4m3fn helpers ----------------
#if __has_builtin(__builtin_amdgcn_cvt_pk_f32_fp8) && __has_builtin(__builtin_amdgcn_cvt_pk_fp8_f32)
#define HAVE_FP8_CVT 1
#endif

#ifndef HAVE_FP8_CVT
__device__ __forceinline__ float fp8_dec1(unsigned b) {
  unsigned s = (b >> 7) & 1u, E = (b >> 3) & 15u, m = b & 7u;
  float v;
  if (E) {
    union { unsigned u; float f; } t;
    t.u = (s << 31) | ((E + 120u) << 23) | (m << 20);
    v = t.f;
  } else {
    v = (s ? -1.f : 1.f) * (float)m * 0.001953125f;
  }
  return v;
}
#endif

template <bool HI>
__device__ __forceinline__ fv2 fp8x2(unsigned u) {
#ifdef HAVE_FP8_CVT
  return __builtin_amdgcn_cvt_pk_f32_fp8((int)u, HI);
#else
  unsigned p = HI ? (u >> 16) : u;
  fv2 r; r.x = fp8_dec1(p & 0xffu); r.y = fp8_dec1((p >> 8) & 0xffu);
  return r;
#endif
}

__device__ __forceinline__ unsigned char f32_to_fp8(float f) {
#ifdef HAVE_FP8_CVT
  return (unsigned char)(__builtin_amdgcn_cvt_pk_fp8_f32(f, f, 0, false) & 0xff);
#else
  union { float f; unsigned u; } t; t.f = f;
  unsigned s = t.u >> 31;
  float a = fabsf(f);
  if (a > 448.f) a = 448.f;
  t.f = a;
  int e = (int)((t.u >> 23) & 0xff) - 127;
  unsigned char r;
  if (a == 0.f) {
    r = 0;
  } else if (e >= -6) {
    unsigned m = t.u & 0x7fffffu;
    unsigned keep = m >> 20, rest = m & 0xfffffu;
    keep += (rest > 0x80000u) || (rest == 0x80000u && (keep & 1u));
    int E = e + 7;
    if (keep == 8u) { keep = 0u; E += 1; }
    if (E >= 16) { E = 15; keep = 6u; }
    r = (unsigned char)((E << 3) | keep);
  } else {
    int mi = (int)(a * 512.f + 0.5f);
    r = (mi > 7) ? (unsigned char)(1u << 3) : (unsigned char)mi;
  }
  return (unsigned char)(r | (s << 7));
#endif
}

// mm from LDS tile: 64 rows x 128 cols, wave = 32r x 64c (B frags hoisted)
__device__ __forceinline__ void mm_lds_fp8(const unsigned short* sA,
                                           const unsigned short* __restrict__ WT,
                                           int n0, int t,
                                           unsigned char* __restrict__ htOut) {
  int wave = t >> 6, lane = t & 63;
  int wr = wave >> 1, wc = wave & 1;
  int m = lane & 15, quad = (lane >> 4) & 3;
  short8 bh[4][4];
#pragma unroll
  for (int q = 0; q < 4; ++q)
#pragma unroll
    for (int ct = 0; ct < 4; ++ct) {
      int n = wc * 64 + ct * 16 + m;
      bh[q][ct] = *(const short8*)(WT + n * H + q * 32 + quad * 8);
    }
  f32x4 acc[2][4];
#pragma unroll
  for (int i = 0; i < 2; ++i)
#pragma unroll
    for (int j = 0; j < 4; ++j) acc[i][j] = (f32x4){0.f, 0.f, 0.f, 0.f};
#pragma unroll
  for (int q = 0; q < 4; ++q) {
    short8 ah[2];
#pragma unroll
    for (int rt = 0; rt < 2; ++rt)
      ah[rt] = *(const short8*)(sA + (wr * 32 + rt * 16 + m) * 136 + q * 32 + quad * 8);
#pragma unroll
    for (int rt = 0; rt < 2; ++rt)
#pragma unroll
      for (int ct = 0; ct < 4; ++ct)
        acc[rt][ct] = __builtin_amdgcn_mfma_f32_16x16x32_bf16(ah[rt], bh[q][ct], acc[rt][ct], 0, 0, 0);
  }
#pragma unroll
  for (int rt = 0; rt < 2; ++rt)
#pragma unroll
    for (int ct = 0; ct < 4; ++ct) {
      int col = wc * 64 + ct * 16 + m;
#pragma unroll
      for (int rr = 0; rr < 4; ++rr) {
        int gn = n0 + wr * 32 + rt * 16 + quad * 4 + rr;
        if (gn < N_NODES) htOut[(size_t)gn * H + col] = f32_to_fp8(acc[rt][ct][rr]);
      }
    }
}

// ---------------- k_embed: embed 64-node tile -> LDS -> mm W0 ----------------
__global__ __launch_bounds__(256) void k_embed(
    const float* __restrict__ x, const float* __restrict__ W_emb,
    const float* __restrict__ b_emb, unsigned short* __restrict__ h,
    const unsigned short* __restrict__ W0T, unsigned char* __restrict__ ht8) {
  __shared__ __align__(16) char smem[25600];
  int t = threadIdx.x;
  int n0 = blockIdx.x * 64;
  float* sW = (float*)smem;
  float* sX = sW + 4096;
  unsigned short* sH = (unsigned short*)smem;
#pragma unroll
  for (int p = 0; p < 4; ++p)
    ((float4*)sW)[t + p * 256] = ((const float4*)W_emb)[t + p * 256];
#pragma unroll
  for (int p = 0; p < 2; ++p) {
    int fi = t * 2 + p;
    int row = fi >> 3, k4 = (fi & 7) * 4;
    int gn = n0 + row; if (gn >= N_NODES) gn = N_NODES - 1;
    *(float4*)(sX + row * 36 + k4) = *(const float4*)(x + (size_t)gn * F_IN + k4);
  }
  __syncthreads();
  // conflict-free sW reads: col0 = (t&3)*4 -> banks {0,4,8,12}(+16i)
  int nr = t >> 2, col0 = (t & 3) * 4;
  float4 acc[8];
#pragma unroll
  for (int i = 0; i < 8; ++i) acc[i] = make_float4(0.f, 0.f, 0.f, 0.f);
#pragma unroll 4
  for (int k = 0; k < F_IN; ++k) {
    float xv = sX[nr * 36 + k];
    const float* wp = sW + k * H + col0;
#pragma unroll
    for (int i = 0; i < 8; ++i) fma4(acc[i], xv, *(const float4*)(wp + i * 16));
  }
#pragma unroll
  for (int i = 0; i < 8; ++i) {
    float4 bv = *(const float4*)(b_emb + col0 + i * 16);
    acc[i].x += bv.x; acc[i].y += bv.y; acc[i].z += bv.z; acc[i].w += bv.w;
  }
  __syncthreads();  // done reading sW/sX; reuse as sH
  int node = n0 + nr;
  unsigned short* hr = h + (size_t)node * H + col0;
#pragma unroll
  for (int i = 0; i < 8; ++i) {
    st_bf4(sH + nr * 136 + col0 + i * 16, acc[i]);
    if (node < N_NODES) st_bf4(hr + i * 16, acc[i]);
  }
  __syncthreads();
  mm_lds_fp8(sH, W0T, n0, t, ht8);
}

// ---------------- k_p1: bucket-bin edges | k_ws weight prep (fused) --------
__global__ __launch_bounds__(512) void k_p1(const int* __restrict__ ei,
                                            int* __restrict__ bcnt,
                                            unsigned* __restrict__ bscr,
                                            const float* __restrict__ W_conv,
                                            const float* __restrict__ W_res,
                                            unsigned short* __restrict__ whiT) {
  __shared__ int hist[NB];
  __shared__ int hbase[NB];
  int t = threadIdx.x;
  if (blockIdx.x >= P1_BLKS) {            // ---- k_ws role: 40 blocks x 2048
    int base = (blockIdx.x - P1_BLKS) * 2048;
#pragma unroll
    for (int j = 0; j < 4; ++j) {
      int idx = base + j * 512 + t;
      int m = idx >> 14, rr = idx & 16383;
      int k = rr >> 7, n = rr & 127;
      const float* src = (m < 4) ? (W_conv + m * H * H) : W_res;
      whiT[m * H * H + n * H + k] = f2bf(src[k * H + n]);
    }
    return;
  }
  for (int i = t; i < NB; i += 512) hist[i] = 0;
  __syncthreads();
  int e0 = blockIdx.x * P1_EPB;
  unsigned pk[P1_EPT]; int br[P1_EPT];
#pragma unroll
  for (int k = 0; k < P1_EPT; ++k) {
    int e = e0 + k * 512 + t;
    if (e < NEDGES) {
      int src = ei[e];
      int dst = ei[NEDGES + e];
      int b = dst >> 7;
      pk[k] = ((unsigned)src << 7) | (unsigned)(dst & 127);
      int r = atomicAdd(&hist[b], 1);        // DS atomic w/ return
      br[k] = (b << 13) | r;                 // r < 8192 always
    } else {
      br[k] = -1; pk[k] = 0;
    }
  }
  __syncthreads();
  for (int i = t; i < NB; i += 512) {
    int c = hist[i];
    hbase[i] = c ? atomicAdd(&bcnt[i], c) : 0;  // global atomic (sparse)
  }
  __syncthreads();
#pragma unroll
  for (int k = 0; k < P1_EPT; ++k) {
    if (br[k] >= 0) {
      int b = br[k] >> 13, r = br[k] & 8191;
      int pos = hbase[b] + r;
      if (pos < BCAP) bscr[(size_t)b * BCAP + pos] = pk[k];  // safety clamp
    }
  }
}

// ---------------- k_scanbc: exclusive scan of bucket counts ----------------
__global__ void k_scanbc(const int* __restrict__ bcnt, int* __restrict__ bbase) {
  __shared__ int s[1024];
  int t = threadIdx.x;
  int d = (t < NB) ? bcnt[t] : 0;
  s[t] = d;
  __syncthreads();
#pragma unroll
  for (int off = 1; off < 1024; off <<= 1) {
    int v = (t >= off) ? s[t - off] : 0;
    __syncthreads();
    s[t] += v;
    __syncthreads();
  }
  if (t < NB) bbase[t] = s[t] - d;
}

// ---------------- k_p2: per-bucket deg/rank (DS atomics) + csr scatter ------
__global__ __launch_bounds__(256) void k_p2(const unsigned* __restrict__ bscr,
                                            const int* __restrict__ bcnt,
                                            const int* __restrict__ bbase,
                                            int* __restrict__ degT,
                                            int* __restrict__ offs,
                                            float* __restrict__ dinv,
                                            unsigned* __restrict__ csr) {
  __shared__ int dl[128], sc[128];
  int b = blockIdx.x, t = threadIdx.x;
  if (t < 128) dl[t] = 0;
  __syncthreads();
  int n = min(bcnt[b], BCAP);
  int base = bbase[b];
  const unsigned* seg = bscr + (size_t)b * BCAP;
  unsigned pk[P2_IT]; unsigned short rr[P2_IT];
#pragma unroll
  for (int k = 0; k < P2_IT; ++k) {
    int i = k * 256 + t;
    if (i < n) {
      unsigned p = seg[i];
      pk[k] = p;
      rr[k] = (unsigned short)atomicAdd(&dl[p & 127u], 1);
    } else pk[k] = 0xffffffffu;   // payload < 2^24, sentinel safe
  }
  __syncthreads();
  if (t < 128) sc[t] = dl[t];
  __syncthreads();
#pragma unroll
  for (int off = 1; off < 128; off <<= 1) {
    int v = (t >= off && t < 128) ? sc[t - off] : 0;
    __syncthreads();
    if (t < 128) sc[t] += v;
    __syncthreads();
  }
  if (t < 128) {
    int node = b * 128 + t;
    if (node < N_NODES) {
      int d = dl[t];
      degT[node] = d;
      dinv[node] = rsqrtf((float)(d + 1));
      offs[node] = base + sc[t] - d;      // absolute exclusive offset
    }
  }
  __syncthreads();
#pragma unroll
  for (int k = 0; k < P2_IT; ++k) {
    if (pk[k] != 0xffffffffu) {
      unsigned p = pk[k];
      unsigned dlo = p & 127u;
      int pos = base + (sc[dlo] - dl[dlo]) + (int)rr[k];
      csr[pos] = (p >> 7) << 15;          // src<<15; w OR'd in k_wq
    }
  }
}

// ---------------- k_wq: OR quantized dinv[src] into csr entries ------------
__global__ __launch_bounds__(256) void k_wq(unsigned* __restrict__ csr,
                                            const float* __restrict__ dinv) {
  int i = (blockIdx.x * 256 + threadIdx.x) * 4;
  if (i < NEDGES) {
    uint4 e = *(uint4*)(csr + i);
    e.x |= (unsigned)(dinv[e.x >> 15] * 32767.f + 0.5f);
    e.y |= (unsigned)(dinv[e.y >> 15] * 32767.f + 0.5f);
    e.z |= (unsigned)(dinv[e.z >> 15] * 32767.f + 0.5f);
    e.w |= (unsigned)(dinv[e.w >> 15] * 32767.f + 0.5f);
    *(uint4*)(csr + i) = e;
  }
}

// ---------------- k_mm: full-width 64x128 tile (r20: A read ONCE) ----------
__global__ __launch_bounds__(256) void k_mm(const unsigned short* __restrict__ A,
                                            const unsigned short* __restrict__ WhiT,
                                            unsigned char* __restrict__ ht8) {
  __shared__ __align__(16) unsigned short sA[64 * 136];
  int t = threadIdx.x;
  int n0 = blockIdx.x * 64;
#pragma unroll
  for (int p = 0; p < 4; ++p) {
    int fi = t + p * 256;
    int row = fi >> 4, c8 = (fi & 15) * 8;
    int gn = n0 + row; if (gn >= N_NODES) gn = N_NODES - 1;
    *(uint4*)(sA + row * 136 + c8) = *(const uint4*)(A + (size_t)gn * H + c8);
  }
  __syncthreads();
  mm_lds_fp8(sA, WhiT, n0, t, ht8);
}

// layer-2 dual GEMM (keeps 64x64 col-split: dual B-frags + dual acc = VGPR cap)
__global__ __launch_bounds__(256) void k_mmd(const unsigned short* __restrict__ A,
    const unsigned short* __restrict__ WcT, const unsigned short* __restrict__ WrT,
    const float* __restrict__ bias,
    unsigned char* __restrict__ ht8, unsigned short* __restrict__ resb) {
  __shared__ __align__(16) unsigned short sA[64 * 136];
  int t = threadIdx.x;
  int j = blockIdx.x;
  int n0 = (j >> 1) * 64, c0 = (j & 1) * 64;
  int wave = t >> 6, lane = t & 63;
  int wr = wave >> 1, wc = wave & 1;
  int m = lane & 15, quad = (lane >> 4) & 3;
  short8 bhc[4][2], bhr[4][2];
#pragma unroll
  for (int q = 0; q < 4; ++q)
#pragma unroll
    for (int ct = 0; ct < 2; ++ct) {
      int n = c0 + wc * 32 + ct * 16 + m;
      bhc[q][ct] = *(const short8*)(WcT + n * H + q * 32 + quad * 8);
      bhr[q][ct] = *(const short8*)(WrT + n * H + q * 32 + quad * 8);
    }
#pragma unroll
  for (int p = 0; p < 4; ++p) {
    int fi = t + p * 256;
    int row = fi >> 4, c8 = (fi & 15) * 8;
    int gn = n0 + row; if (gn >= N_NODES) gn = N_NODES - 1;
    *(uint4*)(sA + row * 136 + c8) = *(const uint4*)(A + (size_t)gn * H + c8);
  }
  __syncthreads();
  f32x4 accC[2][2], accR[2][2];
#pragma unroll
  for (int i = 0; i < 2; ++i)
#pragma unroll
    for (int jj = 0; jj < 2; ++jj) {
      accC[i][jj] = (f32x4){0.f, 0.f, 0.f, 0.f};
      accR[i][jj] = (f32x4){0.f, 0.f, 0.f, 0.f};
    }
#pragma unroll
  for (int q = 0; q < 4; ++q) {
    short8 ah[2];
#pragma unroll
    for (int rt = 0; rt < 2; ++rt)
      ah[rt] = *(const short8*)(sA + (wr * 32 + rt * 16 + m) * 136 + q * 32 + quad * 8);
#pragma unroll
    for (int rt = 0; rt < 2; ++rt)
#pragma unroll
      for (int ct = 0; ct < 2; ++ct) {
        accC[rt][ct] = __builtin_amdgcn_mfma_f32_16x16x32_bf16(ah[rt], bhc[q][ct], accC[rt][ct], 0, 0, 0);
        accR[rt][ct] = __builtin_amdgcn_mfma_f32_16x16x32_bf16(ah[rt], bhr[q][ct], accR[rt][ct], 0, 0, 0);
      }
  }
#pragma unroll
  for (int rt = 0; rt < 2; ++rt)
#pragma unroll
    for (int ct = 0; ct < 2; ++ct) {
      int col = c0 + wc * 32 + ct * 16 + m;
      float bv = bias[col];
#pragma unroll
      for (int rr = 0; rr < 4; ++rr) {
        int gn = n0 + wr * 32 + rt * 16 + quad * 4 + rr;
        if (gn < N_NODES) {
          ht8[(size_t)gn * H + col]  = f32_to_fp8(accC[rt][ct][rr]);
          resb[(size_t)gn * H + col] = f2bf(accR[rt][ct][rr] + bv);
        }
      }
    }
}

// ---------------- aggregate(fp8 ht) + bias + LN + relu + residual(bf16) ----
// r18: one node per 16-lane group (4 nodes/wave). r20: BRANCHLESS 16-deep
// rounds — all 16 gathers issued back-to-back (2x MLP vs 8+branch+8; the
// `if (m>8)` split was blocking load hoisting). Padded slots gather the
// node's own L1-hot row with w=0; only deg<=8 nodes (2.2%) waste slots.
__device__ __forceinline__ void agg_round16(const unsigned char* __restrict__ ht8,
                                            unsigned flo, int gbase,
                                            int s, float w, fv2* acc2) {
  uint2 uu[16]; float ww[16];
#pragma unroll
  for (int jj = 0; jj < 16; ++jj) {
    int ss = __shfl(s, gbase + jj, 64);
    ww[jj] = __shfl(w, gbase + jj, 64);
    uu[jj] = *(const uint2*)(ht8 + (((unsigned)ss << 7) | flo));
  }
#pragma unroll
  for (int jj = 0; jj < 16; ++jj) {
    float we = ww[jj];
    fv2 we2 = {we, we};
    acc2[0] += we2 * fp8x2<false>(uu[jj].x);
    acc2[1] += we2 * fp8x2<true>(uu[jj].x);
    acc2[2] += we2 * fp8x2<false>(uu[jj].y);
    acc2[3] += we2 * fp8x2<true>(uu[jj].y);
  }
}

__global__ __launch_bounds__(512) void k_agg(
    const unsigned char* __restrict__ ht8, const unsigned short* __restrict__ res,
    const float* __restrict__ dinv, const int* __restrict__ offs,
    const int* __restrict__ degT, const unsigned* __restrict__ csr,
    const float* __restrict__ bias, const float* __restrict__ lng,
    const float* __restrict__ lnb, unsigned short* __restrict__ hout) {
  int t = threadIdx.x;
  int fl = t & 15;
  int gbase = t & 48;                    // group base lane within wave
  int node = blockIdx.x * 32 + (t >> 4); // exact: 3125*32 == 100000
  unsigned flo = (unsigned)fl * 8u;
  int start = offs[node], cnt = degT[node];
  float di = dinv[node];
  fv2 acc2[4];
  {
    uint2 u = *(const uint2*)(ht8 + (((unsigned)node << 7) | flo));
    float sw = di * di;
    fv2 sw2 = {sw, sw};
    acc2[0] = sw2 * fp8x2<false>(u.x);
    acc2[1] = sw2 * fp8x2<true>(u.x);
    acc2[2] = sw2 * fp8x2<false>(u.y);
    acc2[3] = sw2 * fp8x2<true>(u.y);
  }
  float ddq = di * (1.f / 32767.f);
  for (int b0 = 0; b0 < cnt; b0 += 16) {
    int s = node; float w = 0.f;
    if (b0 + fl < cnt) {
      unsigned ev = csr[start + b0 + fl];
      s = (int)(ev >> 15);
      w = (float)(ev & 32767u) * ddq;
    }
    agg_round16(ht8, flo, gbase, s, w, acc2);
  }
  float acc[8] = {acc2[0].x, acc2[0].y, acc2[1].x, acc2[1].y,
                  acc2[2].x, acc2[2].y, acc2[3].x, acc2[3].y};
  float4 b0v = *(const float4*)(bias + fl * 8);
  float4 b1v = *(const float4*)(bias + fl * 8 + 4);
  acc[0] += b0v.x; acc[1] += b0v.y; acc[2] += b0v.z; acc[3] += b0v.w;
  acc[4] += b1v.x; acc[5] += b1v.y; acc[6] += b1v.z; acc[7] += b1v.w;
  float sl = ((acc[0] + acc[1]) + (acc[2] + acc[3])) +
             ((acc[4] + acc[5]) + (acc[6] + acc[7]));
#pragma unroll
  for (int mk = 1; mk <= 8; mk <<= 1) sl += __shfl_xor(sl, mk, 16);
  float mu = sl * (1.f / 128.f);
  float d[8];
  float vl = 0.f;
#pragma unroll
  for (int j = 0; j < 8; ++j) { d[j] = acc[j] - mu; vl = fmaf(d[j], d[j], vl); }
#pragma unroll
  for (int mk = 1; mk <= 8; mk <<= 1) vl += __shfl_xor(vl, mk, 16);
  float rs = rsqrtf(vl * (1.f / 128.f) + EPS);
  float4 g0 = *(const float4*)(lng + fl * 8);
  float4 g1 = *(const float4*)(lng + fl * 8 + 4);
  float4 be0 = *(const float4*)(lnb + fl * 8);
  float4 be1 = *(const float4*)(lnb + fl * 8 + 4);
  uint4 rv = *(const uint4*)(res + (size_t)node * 128 + fl * 8);
  float o0 = fmaxf(fmaf(d[0] * rs, g0.x, be0.x), 0.f) + bflo(rv.x);
  float o1 = fmaxf(fmaf(d[1] * rs, g0.y, be0.y), 0.f) + bfhi(rv.x);
  float o2 = fmaxf(fmaf(d[2] * rs, g0.z, be0.z), 0.f) + bflo(rv.y);
  float o3 = fmaxf(fmaf(d[3] * rs, g0.w, be0.w), 0.f) + bfhi(rv.y);
  float o4 = fmaxf(fmaf(d[4] * rs, g1.x, be1.x), 0.f) + bflo(rv.z);
  float o5 = fmaxf(fmaf(d[5] * rs, g1.y, be1.y), 0.f) + bfhi(rv.z);
  float o6 = fmaxf(fmaf(d[6] * rs, g1.z, be1.z), 0.f) + bflo(rv.w);
  float o7 = fmaxf(fmaf(d[7] * rs, g1.w, be1.w), 0.f) + bfhi(rv.w);
  uint4 ov;
  ov.x = pack2(o0, o1); ov.y = pack2(o2, o3);
  ov.z = pack2(o4, o5); ov.w = pack2(o6, o7);
  *(uint4*)(hout + (size_t)node * 128 + fl * 8) = ov;
}

// ---------------- mean pool (bf16 h, vectorized uint4 loads) ----------------
__global__ __launch_bounds__(256) void k_pool(const unsigned short* __restrict__ h,
                                              float* __restrict__ pool) {
  __shared__ float colsum[128];
  int t = threadIdx.x;
  if (t < 128) colsum[t] = 0.f;
  __syncthreads();
  int lr = t >> 4, seg = t & 15;   // 16 rows/pass, 16 x uint4 per row
  float acc[8] = {0.f, 0.f, 0.f, 0.f, 0.f, 0.f, 0.f, 0.f};
  for (int n = blockIdx.x * 16 + lr; n < N_NODES; n += gridDim.x * 16) {
    uint4 u = *(const uint4*)(h + (size_t)n * H + seg * 8);
    acc[0] += bflo(u.x); acc[1] += bfhi(u.x);
    acc[2] += bflo(u.y); acc[3] += bfhi(u.y);
    acc[4] += bflo(u.z); acc[5] += bfhi(u.z);
    acc[6] += bflo(u.w); acc[7] += bfhi(u.w);
  }
#pragma unroll
  for (int j = 0; j < 8; ++j) atomicAdd(&colsum[seg * 8 + j], acc[j]);
  __syncthreads();
  if (t < 128) atomicAdd(&pool[t], colsum[t]);
}

// ---------------- head ----------------
__global__ void k_head(const float* __restrict__ pool, const float* __restrict__ Wfc1,
                       const float* __restrict__ bfc1, const float* __restrict__ g,
                       const float* __restrict__ bb, const float* __restrict__ Wfc2,
                       const float* __restrict__ bfc2, float* __restrict__ out) {
  __shared__ float sm[128], s1[128], stats[2];
  int t = threadIdx.x;
  if (t < 128) sm[t] = pool[t] * (1.f / (float)N_NODES);
  __syncthreads();
  if (t < 128) {
    float a = bfc1[t];
    for (int k = 0; k < 128; ++k) a = fmaf(sm[k], Wfc1[k * 128 + t], a);
    s1[t] = a;
  }
  __syncthreads();
  if (t == 0) {
    float mu = 0.f;
    for (int k = 0; k < 128; ++k) mu += s1[k];
    mu *= (1.f / 128.f);
    float var = 0.f;
    for (int k = 0; k < 128; ++k) { float d = s1[k] - mu; var += d * d; }
    var *= (1.f / 128.f);
    stats[0] = mu; stats[1] = rsqrtf(var + EPS);
  }
  __syncthreads();
  if (t < 128) s1[t] = fmaxf((s1[t] - stats[0]) * stats[1] * g[t] + bb[t], 0.f);
  __syncthreads();
  if (t < OUT_F) {
    float a = bfc2[t];
    for (int k = 0; k < 128; ++k) a = fmaf(s1[k], Wfc2[k * OUT_F + t], a);
    out[t] = a;
  }
}

extern "C" void kernel_launch(void* const* d_in, const int* in_sizes, int n_in,
                              void* d_out, int out_size, void* d_ws, size_t ws_size,
                              hipStream_t stream) {
  const float* x      = (const float*)d_in[0];
  const int*   ei     = (const int*)d_in[1];
  const float* W_emb  = (const float*)d_in[2];
  const float* b_emb  = (const float*)d_in[3];
  const float* W_conv = (const float*)d_in[4];
  const float* b_conv = (const float*)d_in[5];
  const float* ln_g   = (const float*)d_in[6];
  const float* ln_b   = (const float*)d_in[7];
  const float* W_res  = (const float*)d_in[8];
  const float* b_res  = (const float*)d_in[9];
  const float* W_fc1  = (const float*)d_in[10];
  const float* b_fc1  = (const float*)d_in[11];
  const float* fcn_g  = (const float*)d_in[12];
  const float* fcn_b  = (const float*)d_in[13];
  const float* W_fc2  = (const float*)d_in[14];
  const float* b_fc2  = (const float*)d_in[15];
  float* out = (float*)d_out;

  char* p = (char*)d_ws;
  auto take = [&](size_t bytes) {
    char* r = p; p += (bytes + 255) & ~(size_t)255; return r;
  };
  unsigned short* bufA = (unsigned short*)take((size_t)N_NODES * H * 2);
  unsigned short* bufB = (unsigned short*)take((size_t)N_NODES * H * 2);
  unsigned short* bufC = (unsigned short*)take((size_t)N_NODES * H * 2);
  unsigned char*  ht8  = (unsigned char*)take((size_t)N_NODES * H);
  unsigned short* whiT = (unsigned short*)take((size_t)5 * H * H * 2);
  int*   degT = (int*)take(N_NODES * 4);
  int*   offs = (int*)take(N_NODES * 4);
  float* dinv = (float*)take(N_NODES * 4);
  int*   bcnt = (int*)take(NB * 4);
  int*   bbase= (int*)take(NB * 4);
  unsigned* bscr = (unsigned*)take((size_t)NB * BCAP * 4);
  unsigned* csr  = (unsigned*)take((size_t)NEDGES * 4);
  float* pool = (float*)take(128 * 4);

  (void)hipMemsetAsync(bcnt, 0, NB * 4, stream);
  (void)hipMemsetAsync(pool, 0, 128 * 4, stream);

  k_p1<<<P1_BLKS + WS_BLKS, P1_THR, 0, stream>>>(ei, bcnt, bscr,
                                                 W_conv, W_res, whiT);
  k_scanbc<<<1, 1024, 0, stream>>>(bcnt, bbase);
  k_p2<<<NB, 256, 0, stream>>>(bscr, bcnt, bbase, degT, offs, dinv, csr);
  k_wq<<<WQ_BLKS, 256, 0, stream>>>(csr, dinv);
  k_embed<<<TILE_BLKS, 256, 0, stream>>>(x, W_emb, b_emb, bufA,
                                         whiT + 0 * H * H, ht8);

  // L0: res=h0=A -> h1=C
  k_agg<<<AGG_BLKS, 512, 0, stream>>>(ht8, bufA, dinv, offs, degT, csr,
                                      b_conv + 0 * H, ln_g + 0 * H, ln_b + 0 * H, bufC);
  // L1: h1=C -> ht8 -> h2=A (res=C)
  k_mm<<<MM_BLKS, 256, 0, stream>>>(bufC, whiT + 1 * H * H, ht8);
  k_agg<<<AGG_BLKS, 512, 0, stream>>>(ht8, bufC, dinv, offs, degT, csr,
                                      b_conv + 1 * H, ln_g + 1 * H, ln_b + 1 * H, bufA);
  // L2: h2=A; dual: ht8=A@W2, B=bf16(A@Wres+bres); agg -> h3=C (res=B)
  k_mmd<<<MMD_BLKS, 256, 0, stream>>>(bufA, whiT + 2 * H * H, whiT + 4 * H * H,
                                      b_res, ht8, bufB);
  k_agg<<<AGG_BLKS, 512, 0, stream>>>(ht8, bufB, dinv, offs, degT, csr,
                                      b_conv + 2 * H, ln_g + 2 * H, ln_b + 2 * H, bufC);
  // L3: h3=C -> ht8 -> h4=A (res=C)
  k_mm<<<MM_BLKS, 256, 0, stream>>>(bufC, whiT + 3 * H * H, ht8);
  k_agg<<<AGG_BLKS, 512, 0, stream>>>(ht8, bufC, dinv, offs, degT, csr,
                                      b_conv + 3 * H, ln_g + 3 * H, ln_b + 3 * H, bufA);

  k_pool<<<256, 256, 0, stream>>>(bufA, pool);
  k_head<<<1, 256, 0, stream>>>(pool, W_fc1, b_fc1, fcn_g, fcn_b,
                                W_fc2, b_fc2, out);
}